// Round 3
// baseline (741.103 us; speedup 1.0000x reference)
//
#include <hip/hip_runtime.h>
#include <hip/hip_bf16.h>

#define NN 50000
#define NE 800000
#define NG 64
#define DH 128

// ---------------- CSR build ----------------
__global__ void k_hist(const int* __restrict__ ei, int* __restrict__ deg) {
    int i = blockIdx.x * blockDim.x + threadIdx.x;
    if (i < NE) atomicAdd(&deg[ei[NE + i]], 1);
}

__launch_bounds__(1024)
__global__ void k_scan(const int* __restrict__ deg, int* __restrict__ rowptr,
                       int* __restrict__ cursor) {
    __shared__ int sm[1024];
    int t = threadIdx.x;
    const int CH = 49;                       // ceil(50000/1024)
    int b0 = t * CH, b1 = min(b0 + CH, NN);
    int s = 0;
    for (int i = b0; i < b1; ++i) s += deg[i] + 1;   // +1 = self loop
    sm[t] = s;
    __syncthreads();
    for (int off = 1; off < 1024; off <<= 1) {
        int v = (t >= off) ? sm[t - off] : 0;
        __syncthreads();
        sm[t] += v;
        __syncthreads();
    }
    int run = (t > 0) ? sm[t - 1] : 0;
    for (int i = b0; i < b1; ++i) {
        rowptr[i] = run; cursor[i] = run;
        run += deg[i] + 1;
    }
    if (t == 1023) rowptr[NN] = sm[1023];
}

__global__ void k_scatter(const int* __restrict__ ei, int* __restrict__ cursor,
                          int* __restrict__ csr) {
    int i = blockIdx.x * blockDim.x + threadIdx.x;
    if (i < NE) {
        int d = ei[NE + i];
        int p = atomicAdd(&cursor[d], 1);
        csr[p] = ei[i];
    } else if (i < NE + NN) {
        int n = i - NE;
        int p = atomicAdd(&cursor[n], 1);
        csr[p] = n;
    }
}

// ---------------- fp32 GEMM: C[M,128] = A[M,128] @ W[128,128] (+bias,relu) ----
// 64x64 tile, 256 threads, 4x4 per thread, K split in two 64-chunks (32KB LDS).
__launch_bounds__(256)
__global__ void k_gemm(const float* __restrict__ A, const float* __restrict__ W,
                       const float* __restrict__ bias, float* __restrict__ C,
                       int M, int do_relu) {
    __shared__ float As[64 * 64];   // [k_local][col], xor-swizzled columns
    __shared__ float Bs[64 * 64];   // [k_local][col], natural
    int tid = threadIdx.x;
    int row0 = blockIdx.x * 64;
    int col0 = blockIdx.y * 64;
    int tr = tid >> 4, tc = tid & 15;

    float acc[4][4];
    #pragma unroll
    for (int i = 0; i < 4; ++i)
        #pragma unroll
        for (int j = 0; j < 4; ++j) acc[i][j] = 0.f;

    for (int kb = 0; kb < 128; kb += 64) {
        // stage A: 64 rows x 64 k, coalesced loads, swizzled transpose store
        #pragma unroll
        for (int i = 0; i < 16; ++i) {
            int idx = i * 256 + tid;
            int k = idx & 63;      // k_local
            int r = idx >> 6;      // row in tile
            int row = row0 + r;
            float v = (row < M) ? A[(size_t)row * DH + kb + k] : 0.f;
            int col = ((((r >> 2) ^ k) & 15) << 2) | (r & 3);
            As[k * 64 + col] = v;
        }
        // stage B: 64 k x 64 cols of W
        #pragma unroll
        for (int i = 0; i < 8; ++i) {
            int idx = i * 256 + tid;     // 0..2047
            int k = idx >> 5;            // 0..63
            int c2 = (idx & 31) << 1;
            const float* wp = W + (size_t)(kb + k) * DH + col0 + c2;
            float2 u = *(const float2*)wp;
            Bs[k * 64 + c2]     = u.x;
            Bs[k * 64 + c2 + 1] = u.y;
        }
        __syncthreads();

        for (int k = 0; k < 64; ++k) {
            float4 a4 = *(const float4*)&As[k * 64 + (((tr ^ k) & 15) << 2)];
            float4 b4 = *(const float4*)&Bs[k * 64 + (tc << 2)];
            float a[4] = {a4.x, a4.y, a4.z, a4.w};
            float b[4] = {b4.x, b4.y, b4.z, b4.w};
            #pragma unroll
            for (int i = 0; i < 4; ++i)
                #pragma unroll
                for (int j = 0; j < 4; ++j) acc[i][j] += a[i] * b[j];
        }
        __syncthreads();
    }

    float bv[4] = {0.f, 0.f, 0.f, 0.f};
    if (bias) {
        #pragma unroll
        for (int j = 0; j < 4; ++j) bv[j] = bias[col0 + (tc << 2) + j];
    }
    #pragma unroll
    for (int i = 0; i < 4; ++i) {
        int row = row0 + (tr << 2) + i;
        if (row < M) {
            float4 o;
            o.x = acc[i][0] + bv[0];
            o.y = acc[i][1] + bv[1];
            o.z = acc[i][2] + bv[2];
            o.w = acc[i][3] + bv[3];
            if (do_relu) {
                o.x = fmaxf(o.x, 0.f); o.y = fmaxf(o.y, 0.f);
                o.z = fmaxf(o.z, 0.f); o.w = fmaxf(o.w, 0.f);
            }
            *(float4*)(C + (size_t)row * DH + col0 + (tc << 2)) = o;
        }
    }
}

// ---------------- attention logits per node ----------------
__launch_bounds__(256)
__global__ void k_dots(const float* __restrict__ h2, const float* __restrict__ avs,
                       const float* __restrict__ avd, float* __restrict__ asrc,
                       float* __restrict__ adst) {
    int wid = (blockIdx.x * blockDim.x + threadIdx.x) >> 6;
    int lane = threadIdx.x & 63;
    if (wid >= NN) return;
    float2 v = *(const float2*)(h2 + (size_t)wid * DH + lane * 2);
    float s = v.x * avs[lane * 2] + v.y * avs[lane * 2 + 1];
    float d = v.x * avd[lane * 2] + v.y * avd[lane * 2 + 1];
    #pragma unroll
    for (int off = 32; off; off >>= 1) {
        s += __shfl_down(s, off);
        d += __shfl_down(d, off);
    }
    if (lane == 0) { asrc[wid] = s; adst[wid] = d; }
}

// ---------------- fused segment softmax + weighted aggregate ----------------
// one wave per destination node
__launch_bounds__(256)
__global__ void k_aggr(const float* __restrict__ h2, const float* __restrict__ asrc,
                       const float* __restrict__ adst, const int* __restrict__ rowptr,
                       const int* __restrict__ csr, const float* __restrict__ bias,
                       float* __restrict__ hout) {
    int wid = (blockIdx.x * blockDim.x + threadIdx.x) >> 6;
    int lane = threadIdx.x & 63;
    if (wid >= NN) return;
    int beg = rowptr[wid], end = rowptr[wid + 1];
    float ad = adst[wid];

    // pass 1: segment max of leaky_relu(asrc[s]+ad)
    float m = -1e30f;
    for (int i0 = beg; i0 < end; i0 += 64) {
        int i = i0 + lane;
        float e = -1e30f;
        if (i < end) {
            int s = csr[i];
            float t = asrc[s] + ad;
            e = fmaxf(t, 0.f) + 0.2f * fminf(t, 0.f);
        }
        m = fmaxf(m, e);
    }
    #pragma unroll
    for (int off = 32; off; off >>= 1) m = fmaxf(m, __shfl_down(m, off));
    m = __shfl(m, 0);

    // pass 2: unnormalized weights + feature aggregation (float2 per lane)
    float accx = 0.f, accy = 0.f, dsum = 0.f;
    for (int i0 = beg; i0 < end; i0 += 64) {
        int i = i0 + lane;
        int s = 0; float w = 0.f;
        if (i < end) {
            s = csr[i];
            float t = asrc[s] + ad;
            float e = fmaxf(t, 0.f) + 0.2f * fminf(t, 0.f);
            w = __expf(e - m);
        }
        dsum += w;
        int cl = min(64, end - i0);
        for (int j = 0; j < cl; ++j) {
            int   sj = __shfl(s, j);
            float wj = __shfl(w, j);
            float2 v = *(const float2*)(h2 + (size_t)sj * DH + lane * 2);
            accx += wj * v.x;
            accy += wj * v.y;
        }
    }
    #pragma unroll
    for (int off = 32; off; off >>= 1) dsum += __shfl_down(dsum, off);
    dsum = __shfl(dsum, 0);

    float inv = 1.f / (dsum + 1e-16f);
    float bx = bias[lane * 2];
    float by = bias[lane * 2 + 1];
    float2 o;
    o.x = fmaxf(accx * inv + bx, 0.f);
    o.y = fmaxf(accy * inv + by, 0.f);
    *(float2*)(hout + (size_t)wid * DH + lane * 2) = o;
}

// ---------------- mean pool (batch sorted) ----------------
__launch_bounds__(128)
__global__ void k_pool(const float* __restrict__ h, const int* __restrict__ batch,
                       float* __restrict__ gsum, int* __restrict__ gcnt) {
    int f = threadIdx.x;                  // 0..127
    int n0 = blockIdx.x * 64;
    int n1 = min(n0 + 64, NN);
    float acc = 0.f; int run = 0;
    int gcur = batch[n0];
    for (int nd = n0; nd < n1; ++nd) {
        int g = batch[nd];
        if (g != gcur) {
            atomicAdd(&gsum[gcur * DH + f], acc);
            if (f == 0) atomicAdd(&gcnt[gcur], run);
            acc = 0.f; run = 0; gcur = g;
        }
        acc += h[(size_t)nd * DH + f];
        run += 1;
    }
    atomicAdd(&gsum[gcur * DH + f], acc);
    if (f == 0) atomicAdd(&gcnt[gcur], run);
}

// ---------------- final linear [64,128]@[128,10] -> fp32 out ----------------
__global__ void k_final(const float* __restrict__ gsum, const int* __restrict__ gcnt,
                        const float* __restrict__ W1, const float* __restrict__ b1,
                        float* __restrict__ out) {
    int t = threadIdx.x;
    if (t >= NG * 10) return;
    int g = t / 10, o = t % 10;
    float inv = 1.f / fmaxf((float)gcnt[g], 1.f);
    float acc = 0.f;
    for (int f = 0; f < DH; ++f) acc += gsum[g * DH + f] * W1[f * 10 + o];
    out[t] = acc * inv + b1[o];
}

extern "C" void kernel_launch(void* const* d_in, const int* in_sizes, int n_in,
                              void* d_out, int out_size, void* d_ws, size_t ws_size,
                              hipStream_t stream) {
    const float* x       = (const float*)d_in[0];
    const int*   ei      = (const int*)d_in[1];
    const int*   batch   = (const int*)d_in[3];
    const float* W0      = (const float*)d_in[4];
    const float* b0      = (const float*)d_in[5];
    const float* Wc      = (const float*)d_in[6];
    const float* att_src = (const float*)d_in[7];
    const float* att_dst = (const float*)d_in[8];
    const float* bc      = (const float*)d_in[9];
    const float* W1      = (const float*)d_in[10];
    const float* b1      = (const float*)d_in[11];
    float* out = (float*)d_out;

    char* ws = (char*)d_ws;
    size_t off = 0;
    auto alloc = [&](size_t bytes) {
        void* p = ws + off;
        off += (bytes + 255) & ~(size_t)255;
        return p;
    };
    float* hA     = (float*)alloc((size_t)NN * DH * 4);
    float* hB     = (float*)alloc((size_t)NN * DH * 4);
    int*   rowptr = (int*)alloc((NN + 1) * 4);
    int*   cursor = (int*)alloc(NN * 4);
    int*   csr    = (int*)alloc((NE + NN) * 4);
    float* asrc   = (float*)alloc(NN * 4);
    float* adst   = (float*)alloc(NN * 4);
    int*   deg    = (int*)alloc(NN * 4);
    float* gsum   = (float*)alloc(NG * DH * 4);   // gsum+gcnt adjacent (both 256-pad)
    int*   gcnt   = (int*)alloc(NG * 4);

    hipMemsetAsync(deg, 0, NN * 4, stream);
    hipMemsetAsync(gsum, 0, NG * DH * 4 + 256, stream);  // covers gcnt too

    k_hist<<<(NE + 255) / 256, 256, 0, stream>>>(ei, deg);
    k_scan<<<1, 1024, 0, stream>>>(deg, rowptr, cursor);
    k_scatter<<<(NE + NN + 255) / 256, 256, 0, stream>>>(ei, cursor, csr);

    dim3 gg((NN + 63) / 64, 2);
    k_gemm<<<gg, 256, 0, stream>>>(x, W0, b0, hB, NN, 1);

    for (int l = 0; l < 3; ++l) {
        k_gemm<<<gg, 256, 0, stream>>>(hB, Wc + (size_t)l * DH * DH, nullptr, hA, NN, 0);
        k_dots<<<(NN + 3) / 4, 256, 0, stream>>>(hA, att_src + l * DH, att_dst + l * DH, asrc, adst);
        k_aggr<<<(NN + 3) / 4, 256, 0, stream>>>(hA, asrc, adst, rowptr, csr, bc + l * DH, hB);
    }

    k_pool<<<(NN + 63) / 64, 128, 0, stream>>>(hB, batch, gsum, gcnt);
    k_final<<<1, NG * 10, 0, stream>>>(gsum, gcnt, W1, b1, out);
}

// Round 4
// 635.803 us; speedup vs baseline: 1.1656x; 1.1656x over previous
//
#include <hip/hip_runtime.h>
#include <hip/hip_bf16.h>

#define NN 50000
#define NE 800000
#define NG 64
#define DH 128

#define SCB 4096                         // scan elements per block
#define NSCB ((NN + SCB - 1) / SCB)      // 13

// ---------------- CSR build ----------------
__global__ void k_hist(const int* __restrict__ ei, int* __restrict__ deg) {
    int i = blockIdx.x * blockDim.x + threadIdx.x;
    if (i < NE) atomicAdd(&deg[ei[NE + i]], 1);
}

// phase 1: per-block sums of (deg[i]+1)
__launch_bounds__(256)
__global__ void k_bsum(const int* __restrict__ deg, int* __restrict__ bsum) {
    int t = threadIdx.x;
    int base = blockIdx.x * SCB + t * 16;
    int s = 0;
    #pragma unroll
    for (int j = 0; j < 16; ++j) {
        int i = base + j;
        if (i < NN) s += deg[i] + 1;     // +1 = self loop
    }
    #pragma unroll
    for (int off = 32; off; off >>= 1) s += __shfl_down(s, off);
    __shared__ int ws[4];
    if ((t & 63) == 0) ws[t >> 6] = s;
    __syncthreads();
    if (t == 0) bsum[blockIdx.x] = ws[0] + ws[1] + ws[2] + ws[3];
}

// phase 2: scan the 13 block sums (single wave)
__global__ void k_base(const int* __restrict__ bsum, int* __restrict__ bbase,
                       int* __restrict__ rowptr) {
    int t = threadIdx.x;                 // 64 threads
    int orig = (t < NSCB) ? bsum[t] : 0;
    int v = orig;
    #pragma unroll
    for (int off = 1; off < 64; off <<= 1) {
        int u = __shfl_up(v, off);
        if (t >= off) v += u;
    }
    if (t < NSCB) bbase[t] = v - orig;   // exclusive
    if (t == 63) rowptr[NN] = v;         // grand total (= NE + NN)
}

// phase 3: apply — full exclusive scan, write rowptr + cursor
__launch_bounds__(256)
__global__ void k_apply(const int* __restrict__ deg, const int* __restrict__ bbase,
                        int* __restrict__ rowptr, int* __restrict__ cursor) {
    int t = threadIdx.x;
    int base = blockIdx.x * SCB + t * 16;
    int v[16];
    int s = 0;
    #pragma unroll
    for (int j = 0; j < 16; ++j) {
        int i = base + j;
        v[j] = (i < NN) ? (deg[i] + 1) : 0;
        s += v[j];
    }
    int inc = s;                          // inclusive scan within wave
    #pragma unroll
    for (int off = 1; off < 64; off <<= 1) {
        int u = __shfl_up(inc, off);
        if ((t & 63) >= off) inc += u;
    }
    __shared__ int wsum[4];
    if ((t & 63) == 63) wsum[t >> 6] = inc;
    __syncthreads();
    int w = t >> 6;
    int woff = 0;
    #pragma unroll
    for (int k = 0; k < 4; ++k) if (k < w) woff += wsum[k];
    int run = inc - s + woff + bbase[blockIdx.x];
    #pragma unroll
    for (int j = 0; j < 16; ++j) {
        int i = base + j;
        if (i < NN) { rowptr[i] = run; cursor[i] = run; }
        run += v[j];
    }
}

__global__ void k_scatter(const int* __restrict__ ei, int* __restrict__ cursor,
                          int* __restrict__ csr) {
    int i = blockIdx.x * blockDim.x + threadIdx.x;
    if (i < NE) {
        int d = ei[NE + i];
        int p = atomicAdd(&cursor[d], 1);
        csr[p] = ei[i];
    } else if (i < NE + NN) {
        int n = i - NE;
        int p = atomicAdd(&cursor[n], 1);
        csr[p] = n;
    }
}

// ---------------- fp32 GEMM: C[M,128] = A[M,128] @ W[128,128] (+bias,relu) ----
// 64x64 tile, 256 threads, 4x4 per thread, K split in two 64-chunks (32KB LDS).
__launch_bounds__(256)
__global__ void k_gemm(const float* __restrict__ A, const float* __restrict__ W,
                       const float* __restrict__ bias, float* __restrict__ C,
                       int M, int do_relu) {
    __shared__ float As[64 * 64];   // [k_local][col], xor-swizzled columns
    __shared__ float Bs[64 * 64];   // [k_local][col], natural
    int tid = threadIdx.x;
    int row0 = blockIdx.x * 64;
    int col0 = blockIdx.y * 64;
    int tr = tid >> 4, tc = tid & 15;

    float acc[4][4];
    #pragma unroll
    for (int i = 0; i < 4; ++i)
        #pragma unroll
        for (int j = 0; j < 4; ++j) acc[i][j] = 0.f;

    for (int kb = 0; kb < 128; kb += 64) {
        #pragma unroll
        for (int i = 0; i < 16; ++i) {
            int idx = i * 256 + tid;
            int k = idx & 63;
            int r = idx >> 6;
            int row = row0 + r;
            float v = (row < M) ? A[(size_t)row * DH + kb + k] : 0.f;
            int col = ((((r >> 2) ^ k) & 15) << 2) | (r & 3);
            As[k * 64 + col] = v;
        }
        #pragma unroll
        for (int i = 0; i < 8; ++i) {
            int idx = i * 256 + tid;
            int k = idx >> 5;
            int c2 = (idx & 31) << 1;
            const float* wp = W + (size_t)(kb + k) * DH + col0 + c2;
            float2 u = *(const float2*)wp;
            Bs[k * 64 + c2]     = u.x;
            Bs[k * 64 + c2 + 1] = u.y;
        }
        __syncthreads();

        for (int k = 0; k < 64; ++k) {
            float4 a4 = *(const float4*)&As[k * 64 + (((tr ^ k) & 15) << 2)];
            float4 b4 = *(const float4*)&Bs[k * 64 + (tc << 2)];
            float a[4] = {a4.x, a4.y, a4.z, a4.w};
            float b[4] = {b4.x, b4.y, b4.z, b4.w};
            #pragma unroll
            for (int i = 0; i < 4; ++i)
                #pragma unroll
                for (int j = 0; j < 4; ++j) acc[i][j] += a[i] * b[j];
        }
        __syncthreads();
    }

    float bv[4] = {0.f, 0.f, 0.f, 0.f};
    if (bias) {
        #pragma unroll
        for (int j = 0; j < 4; ++j) bv[j] = bias[col0 + (tc << 2) + j];
    }
    #pragma unroll
    for (int i = 0; i < 4; ++i) {
        int row = row0 + (tr << 2) + i;
        if (row < M) {
            float4 o;
            o.x = acc[i][0] + bv[0];
            o.y = acc[i][1] + bv[1];
            o.z = acc[i][2] + bv[2];
            o.w = acc[i][3] + bv[3];
            if (do_relu) {
                o.x = fmaxf(o.x, 0.f); o.y = fmaxf(o.y, 0.f);
                o.z = fmaxf(o.z, 0.f); o.w = fmaxf(o.w, 0.f);
            }
            *(float4*)(C + (size_t)row * DH + col0 + (tc << 2)) = o;
        }
    }
}

// ---------------- attention logits per node ----------------
__launch_bounds__(256)
__global__ void k_dots(const float* __restrict__ h2, const float* __restrict__ avs,
                       const float* __restrict__ avd, float* __restrict__ asrc,
                       float* __restrict__ adst) {
    int wid = (blockIdx.x * blockDim.x + threadIdx.x) >> 6;
    int lane = threadIdx.x & 63;
    if (wid >= NN) return;
    float2 v = *(const float2*)(h2 + (size_t)wid * DH + lane * 2);
    float s = v.x * avs[lane * 2] + v.y * avs[lane * 2 + 1];
    float d = v.x * avd[lane * 2] + v.y * avd[lane * 2 + 1];
    #pragma unroll
    for (int off = 32; off; off >>= 1) {
        s += __shfl_down(s, off);
        d += __shfl_down(d, off);
    }
    if (lane == 0) { asrc[wid] = s; adst[wid] = d; }
}

// ---------------- fused segment softmax + weighted aggregate ----------------
__launch_bounds__(256)
__global__ void k_aggr(const float* __restrict__ h2, const float* __restrict__ asrc,
                       const float* __restrict__ adst, const int* __restrict__ rowptr,
                       const int* __restrict__ csr, const float* __restrict__ bias,
                       float* __restrict__ hout) {
    int wid = (blockIdx.x * blockDim.x + threadIdx.x) >> 6;
    int lane = threadIdx.x & 63;
    if (wid >= NN) return;
    int beg = rowptr[wid], end = rowptr[wid + 1];
    float ad = adst[wid];

    float m = -1e30f;
    for (int i0 = beg; i0 < end; i0 += 64) {
        int i = i0 + lane;
        float e = -1e30f;
        if (i < end) {
            int s = csr[i];
            float t = asrc[s] + ad;
            e = fmaxf(t, 0.f) + 0.2f * fminf(t, 0.f);
        }
        m = fmaxf(m, e);
    }
    #pragma unroll
    for (int off = 32; off; off >>= 1) m = fmaxf(m, __shfl_down(m, off));
    m = __shfl(m, 0);

    float accx = 0.f, accy = 0.f, dsum = 0.f;
    for (int i0 = beg; i0 < end; i0 += 64) {
        int i = i0 + lane;
        int s = 0; float w = 0.f;
        if (i < end) {
            s = csr[i];
            float t = asrc[s] + ad;
            float e = fmaxf(t, 0.f) + 0.2f * fminf(t, 0.f);
            w = __expf(e - m);
        }
        dsum += w;
        int cl = min(64, end - i0);
        for (int j = 0; j < cl; ++j) {
            int   sj = __shfl(s, j);
            float wj = __shfl(w, j);
            float2 v = *(const float2*)(h2 + (size_t)sj * DH + lane * 2);
            accx += wj * v.x;
            accy += wj * v.y;
        }
    }
    #pragma unroll
    for (int off = 32; off; off >>= 1) dsum += __shfl_down(dsum, off);
    dsum = __shfl(dsum, 0);

    float inv = 1.f / (dsum + 1e-16f);
    float bx = bias[lane * 2];
    float by = bias[lane * 2 + 1];
    float2 o;
    o.x = fmaxf(accx * inv + bx, 0.f);
    o.y = fmaxf(accy * inv + by, 0.f);
    *(float2*)(hout + (size_t)wid * DH + lane * 2) = o;
}

// ---------------- mean pool (batch sorted) ----------------
__launch_bounds__(128)
__global__ void k_pool(const float* __restrict__ h, const int* __restrict__ batch,
                       float* __restrict__ gsum, int* __restrict__ gcnt) {
    int f = threadIdx.x;
    int n0 = blockIdx.x * 64;
    int n1 = min(n0 + 64, NN);
    float acc = 0.f; int run = 0;
    int gcur = batch[n0];
    for (int nd = n0; nd < n1; ++nd) {
        int g = batch[nd];
        if (g != gcur) {
            atomicAdd(&gsum[gcur * DH + f], acc);
            if (f == 0) atomicAdd(&gcnt[gcur], run);
            acc = 0.f; run = 0; gcur = g;
        }
        acc += h[(size_t)nd * DH + f];
        run += 1;
    }
    atomicAdd(&gsum[gcur * DH + f], acc);
    if (f == 0) atomicAdd(&gcnt[gcur], run);
}

// ---------------- final linear [64,128]@[128,10] -> fp32 out ----------------
__global__ void k_final(const float* __restrict__ gsum, const int* __restrict__ gcnt,
                        const float* __restrict__ W1, const float* __restrict__ b1,
                        float* __restrict__ out) {
    int t = threadIdx.x;
    if (t >= NG * 10) return;
    int g = t / 10, o = t % 10;
    float inv = 1.f / fmaxf((float)gcnt[g], 1.f);
    float acc = 0.f;
    for (int f = 0; f < DH; ++f) acc += gsum[g * DH + f] * W1[f * 10 + o];
    out[t] = acc * inv + b1[o];
}

extern "C" void kernel_launch(void* const* d_in, const int* in_sizes, int n_in,
                              void* d_out, int out_size, void* d_ws, size_t ws_size,
                              hipStream_t stream) {
    const float* x       = (const float*)d_in[0];
    const int*   ei      = (const int*)d_in[1];
    const int*   batch   = (const int*)d_in[3];
    const float* W0      = (const float*)d_in[4];
    const float* b0      = (const float*)d_in[5];
    const float* Wc      = (const float*)d_in[6];
    const float* att_src = (const float*)d_in[7];
    const float* att_dst = (const float*)d_in[8];
    const float* bc      = (const float*)d_in[9];
    const float* W1      = (const float*)d_in[10];
    const float* b1      = (const float*)d_in[11];
    float* out = (float*)d_out;

    char* ws = (char*)d_ws;
    size_t off = 0;
    auto alloc = [&](size_t bytes) {
        void* p = ws + off;
        off += (bytes + 255) & ~(size_t)255;
        return p;
    };
    float* hA     = (float*)alloc((size_t)NN * DH * 4);
    float* hB     = (float*)alloc((size_t)NN * DH * 4);
    int*   rowptr = (int*)alloc((NN + 1) * 4);
    int*   cursor = (int*)alloc(NN * 4);
    int*   csr    = (int*)alloc((NE + NN) * 4);
    float* asrc   = (float*)alloc(NN * 4);
    float* adst   = (float*)alloc(NN * 4);
    int*   deg    = (int*)alloc(NN * 4);
    int*   bsum   = (int*)alloc(64 * 4);
    int*   bbase  = (int*)alloc(64 * 4);
    float* gsum   = (float*)alloc(NG * DH * 4);   // gsum+gcnt adjacent (both 256-pad)
    int*   gcnt   = (int*)alloc(NG * 4);

    hipMemsetAsync(deg, 0, NN * 4, stream);
    hipMemsetAsync(gsum, 0, NG * DH * 4 + 256, stream);  // covers gcnt too

    k_hist<<<(NE + 255) / 256, 256, 0, stream>>>(ei, deg);
    k_bsum<<<NSCB, 256, 0, stream>>>(deg, bsum);
    k_base<<<1, 64, 0, stream>>>(bsum, bbase, rowptr);
    k_apply<<<NSCB, 256, 0, stream>>>(deg, bbase, rowptr, cursor);
    k_scatter<<<(NE + NN + 255) / 256, 256, 0, stream>>>(ei, cursor, csr);

    dim3 gg((NN + 63) / 64, 2);
    k_gemm<<<gg, 256, 0, stream>>>(x, W0, b0, hB, NN, 1);

    for (int l = 0; l < 3; ++l) {
        k_gemm<<<gg, 256, 0, stream>>>(hB, Wc + (size_t)l * DH * DH, nullptr, hA, NN, 0);
        k_dots<<<(NN + 3) / 4, 256, 0, stream>>>(hA, att_src + l * DH, att_dst + l * DH, asrc, adst);
        k_aggr<<<(NN + 3) / 4, 256, 0, stream>>>(hA, asrc, adst, rowptr, csr, bc + l * DH, hB);
    }

    k_pool<<<(NN + 63) / 64, 128, 0, stream>>>(hB, batch, gsum, gcnt);
    k_final<<<1, NG * 10, 0, stream>>>(gsum, gcnt, W1, b1, out);
}

// Round 5
// 542.828 us; speedup vs baseline: 1.3653x; 1.1713x over previous
//
#include <hip/hip_runtime.h>
#include <hip/hip_bf16.h>

#define NN 50000
#define NE 800000
#define NG 64
#define DH 128

#define SCB 4096                         // scan elements per block
#define NSCB ((NN + SCB - 1) / SCB)      // 13

typedef __bf16 bfx8 __attribute__((ext_vector_type(8)));
typedef float  f32x4 __attribute__((ext_vector_type(4)));

__device__ __forceinline__ ushort f2b(float f) {        // fp32 -> bf16 RNE
    unsigned b = __float_as_uint(f);
    b += 0x7fff + ((b >> 16) & 1);
    return (ushort)(b >> 16);
}
__device__ __forceinline__ float b2f(ushort s) {
    return __uint_as_float((unsigned)s << 16);
}

// ---------------- CSR build ----------------
__global__ void k_hist(const int* __restrict__ ei, int* __restrict__ deg) {
    int i = blockIdx.x * blockDim.x + threadIdx.x;
    if (i < NE) atomicAdd(&deg[ei[NE + i]], 1);
}

__launch_bounds__(256)
__global__ void k_bsum(const int* __restrict__ deg, int* __restrict__ bsum) {
    int t = threadIdx.x;
    int base = blockIdx.x * SCB + t * 16;
    int s = 0;
    #pragma unroll
    for (int j = 0; j < 16; ++j) {
        int i = base + j;
        if (i < NN) s += deg[i] + 1;     // +1 = self loop
    }
    #pragma unroll
    for (int off = 32; off; off >>= 1) s += __shfl_down(s, off);
    __shared__ int ws[4];
    if ((t & 63) == 0) ws[t >> 6] = s;
    __syncthreads();
    if (t == 0) bsum[blockIdx.x] = ws[0] + ws[1] + ws[2] + ws[3];
}

__global__ void k_base(const int* __restrict__ bsum, int* __restrict__ bbase,
                       int* __restrict__ rowptr) {
    int t = threadIdx.x;                 // 64 threads
    int orig = (t < NSCB) ? bsum[t] : 0;
    int v = orig;
    #pragma unroll
    for (int off = 1; off < 64; off <<= 1) {
        int u = __shfl_up(v, off);
        if (t >= off) v += u;
    }
    if (t < NSCB) bbase[t] = v - orig;   // exclusive
    if (t == 63) rowptr[NN] = v;         // grand total (= NE + NN)
}

__launch_bounds__(256)
__global__ void k_apply(const int* __restrict__ deg, const int* __restrict__ bbase,
                        int* __restrict__ rowptr, int* __restrict__ cursor) {
    int t = threadIdx.x;
    int base = blockIdx.x * SCB + t * 16;
    int v[16];
    int s = 0;
    #pragma unroll
    for (int j = 0; j < 16; ++j) {
        int i = base + j;
        v[j] = (i < NN) ? (deg[i] + 1) : 0;
        s += v[j];
    }
    int inc = s;
    #pragma unroll
    for (int off = 1; off < 64; off <<= 1) {
        int u = __shfl_up(inc, off);
        if ((t & 63) >= off) inc += u;
    }
    __shared__ int wsum[4];
    if ((t & 63) == 63) wsum[t >> 6] = inc;
    __syncthreads();
    int w = t >> 6;
    int woff = 0;
    #pragma unroll
    for (int k = 0; k < 4; ++k) if (k < w) woff += wsum[k];
    int run = inc - s + woff + bbase[blockIdx.x];
    #pragma unroll
    for (int j = 0; j < 16; ++j) {
        int i = base + j;
        if (i < NN) { rowptr[i] = run; cursor[i] = run; }
        run += v[j];
    }
}

__global__ void k_scatter(const int* __restrict__ ei, int* __restrict__ cursor,
                          int* __restrict__ csr) {
    int i = blockIdx.x * blockDim.x + threadIdx.x;
    if (i < NE) {
        int d = ei[NE + i];
        int p = atomicAdd(&cursor[d], 1);
        csr[p] = ei[i];
    } else if (i < NE + NN) {
        int n = i - NE;
        int p = atomicAdd(&cursor[n], 1);
        csr[p] = n;
    }
}

// ---------------- weight transpose+convert: Wt[n][k] bf16 ----------------
// matrix 0 = W0, matrices 1..3 = Wc layers
__global__ void k_wt(const float* __restrict__ W0, const float* __restrict__ Wc,
                     ushort* __restrict__ Wt) {
    int i = blockIdx.x * 256 + threadIdx.x;   // 0 .. 4*16384-1
    int m = i >> 14;
    int r = i & 16383;
    int k = r >> 7, n = r & 127;
    const float* src = (m == 0) ? W0 : (Wc + (size_t)(m - 1) * DH * DH);
    Wt[(size_t)m * DH * DH + n * DH + k] = f2b(src[r]);
}

// ---------------- MFMA GEMM: C[M,128] = A[M,128] @ W  (Wt = W^T bf16) -------
// one wave per 16 rows; no LDS, no barriers. A/B frags loaded straight from
// global (16 B/lane); D layout: col=lane&15, row=quad*4+reg (verified m89).
template<bool AF32>
__launch_bounds__(256)
__global__ void k_gemm_mfma(const void* __restrict__ Av, const ushort* __restrict__ Wt,
                            const float* __restrict__ bias, ushort* __restrict__ C,
                            int relu) {
    int wid = (blockIdx.x * blockDim.x + threadIdx.x) >> 6;
    int lane = threadIdx.x & 63;
    int row0 = wid * 16;
    if (row0 >= NN) return;
    int mrow = lane & 15;
    int quad = lane >> 4;
    int arow = row0 + mrow;

    f32x4 acc[8];
    #pragma unroll
    for (int t = 0; t < 8; ++t)
        #pragma unroll
        for (int r = 0; r < 4; ++r) acc[t][r] = 0.f;

    #pragma unroll
    for (int ks = 0; ks < 4; ++ks) {
        int k0 = ks * 32 + quad * 8;
        bfx8 a;
        if (AF32) {
            const float* ap = (const float*)Av + (size_t)arow * DH + k0;
            union { ushort s[8]; bfx8 v; } u;
            #pragma unroll
            for (int j = 0; j < 8; ++j) u.s[j] = f2b(ap[j]);
            a = u.v;
        } else {
            a = *(const bfx8*)((const ushort*)Av + (size_t)arow * DH + k0);
        }
        #pragma unroll
        for (int t = 0; t < 8; ++t) {
            bfx8 b = *(const bfx8*)(Wt + (size_t)(t * 16 + mrow) * DH + k0);
            acc[t] = __builtin_amdgcn_mfma_f32_16x16x32_bf16(a, b, acc[t], 0, 0, 0);
        }
    }

    int orow = row0 + quad * 4;
    #pragma unroll
    for (int t = 0; t < 8; ++t) {
        int col = t * 16 + mrow;
        float bv = bias ? bias[col] : 0.f;
        #pragma unroll
        for (int r = 0; r < 4; ++r) {
            float v = acc[t][r] + bv;
            if (relu) v = fmaxf(v, 0.f);
            C[(size_t)(orow + r) * DH + col] = f2b(v);
        }
    }
}

// ---------------- attention logits per node (bf16 h) ----------------
__launch_bounds__(256)
__global__ void k_dots(const ushort* __restrict__ h, const float* __restrict__ avs,
                       const float* __restrict__ avd, float* __restrict__ asrc,
                       float* __restrict__ adst) {
    int wid = (blockIdx.x * blockDim.x + threadIdx.x) >> 6;
    int lane = threadIdx.x & 63;
    if (wid >= NN) return;
    unsigned u = *(const unsigned*)(h + (size_t)wid * DH + lane * 2);
    float vx = __uint_as_float(u << 16);
    float vy = __uint_as_float(u & 0xffff0000u);
    float s = vx * avs[lane * 2] + vy * avs[lane * 2 + 1];
    float d = vx * avd[lane * 2] + vy * avd[lane * 2 + 1];
    #pragma unroll
    for (int off = 32; off; off >>= 1) {
        s += __shfl_down(s, off);
        d += __shfl_down(d, off);
    }
    if (lane == 0) { asrc[wid] = s; adst[wid] = d; }
}

// ---------------- fused segment softmax + weighted aggregate (bf16 h) -------
__launch_bounds__(256)
__global__ void k_aggr(const ushort* __restrict__ h, const float* __restrict__ asrc,
                       const float* __restrict__ adst, const int* __restrict__ rowptr,
                       const int* __restrict__ csr, const float* __restrict__ bias,
                       ushort* __restrict__ hout) {
    int wid = (blockIdx.x * blockDim.x + threadIdx.x) >> 6;
    int lane = threadIdx.x & 63;
    if (wid >= NN) return;
    int beg = rowptr[wid], end = rowptr[wid + 1];
    float ad = adst[wid];

    float m = -1e30f;
    for (int i0 = beg; i0 < end; i0 += 64) {
        int i = i0 + lane;
        float e = -1e30f;
        if (i < end) {
            int s = csr[i];
            float t = asrc[s] + ad;
            e = fmaxf(t, 0.f) + 0.2f * fminf(t, 0.f);
        }
        m = fmaxf(m, e);
    }
    #pragma unroll
    for (int off = 32; off; off >>= 1) m = fmaxf(m, __shfl_down(m, off));
    m = __shfl(m, 0);

    float accx = 0.f, accy = 0.f, dsum = 0.f;
    for (int i0 = beg; i0 < end; i0 += 64) {
        int i = i0 + lane;
        int s = 0; float w = 0.f;
        if (i < end) {
            s = csr[i];
            float t = asrc[s] + ad;
            float e = fmaxf(t, 0.f) + 0.2f * fminf(t, 0.f);
            w = __expf(e - m);
        }
        dsum += w;
        int cl = min(64, end - i0);
        for (int j = 0; j < cl; ++j) {
            int   sj = __shfl(s, j);
            float wj = __shfl(w, j);
            unsigned u = *(const unsigned*)(h + (size_t)sj * DH + lane * 2);
            accx += wj * __uint_as_float(u << 16);
            accy += wj * __uint_as_float(u & 0xffff0000u);
        }
    }
    #pragma unroll
    for (int off = 32; off; off >>= 1) dsum += __shfl_down(dsum, off);
    dsum = __shfl(dsum, 0);

    float inv = 1.f / (dsum + 1e-16f);
    float ox = fmaxf(accx * inv + bias[lane * 2], 0.f);
    float oy = fmaxf(accy * inv + bias[lane * 2 + 1], 0.f);
    unsigned pk = (unsigned)f2b(ox) | ((unsigned)f2b(oy) << 16);
    *(unsigned*)(hout + (size_t)wid * DH + lane * 2) = pk;
}

// ---------------- mean pool (batch sorted, bf16 h) ----------------
__launch_bounds__(128)
__global__ void k_pool(const ushort* __restrict__ h, const int* __restrict__ batch,
                       float* __restrict__ gsum, int* __restrict__ gcnt) {
    int f = threadIdx.x;
    int n0 = blockIdx.x * 64;
    int n1 = min(n0 + 64, NN);
    float acc = 0.f; int run = 0;
    int gcur = batch[n0];
    for (int nd = n0; nd < n1; ++nd) {
        int g = batch[nd];
        if (g != gcur) {
            atomicAdd(&gsum[gcur * DH + f], acc);
            if (f == 0) atomicAdd(&gcnt[gcur], run);
            acc = 0.f; run = 0; gcur = g;
        }
        acc += b2f(h[(size_t)nd * DH + f]);
        run += 1;
    }
    atomicAdd(&gsum[gcur * DH + f], acc);
    if (f == 0) atomicAdd(&gcnt[gcur], run);
}

// ---------------- final linear [64,128]@[128,10] -> fp32 out ----------------
__global__ void k_final(const float* __restrict__ gsum, const int* __restrict__ gcnt,
                        const float* __restrict__ W1, const float* __restrict__ b1,
                        float* __restrict__ out) {
    int t = threadIdx.x;
    if (t >= NG * 10) return;
    int g = t / 10, o = t % 10;
    float inv = 1.f / fmaxf((float)gcnt[g], 1.f);
    float acc = 0.f;
    for (int f = 0; f < DH; ++f) acc += gsum[g * DH + f] * W1[f * 10 + o];
    out[t] = acc * inv + b1[o];
}

extern "C" void kernel_launch(void* const* d_in, const int* in_sizes, int n_in,
                              void* d_out, int out_size, void* d_ws, size_t ws_size,
                              hipStream_t stream) {
    const float* x       = (const float*)d_in[0];
    const int*   ei      = (const int*)d_in[1];
    const int*   batch   = (const int*)d_in[3];
    const float* W0      = (const float*)d_in[4];
    const float* b0      = (const float*)d_in[5];
    const float* Wc      = (const float*)d_in[6];
    const float* att_src = (const float*)d_in[7];
    const float* att_dst = (const float*)d_in[8];
    const float* bc      = (const float*)d_in[9];
    const float* W1      = (const float*)d_in[10];
    const float* b1      = (const float*)d_in[11];
    float* out = (float*)d_out;

    char* ws = (char*)d_ws;
    size_t off = 0;
    auto alloc = [&](size_t bytes) {
        void* p = ws + off;
        off += (bytes + 255) & ~(size_t)255;
        return p;
    };
    ushort* hA     = (ushort*)alloc((size_t)NN * DH * 2);
    ushort* hB     = (ushort*)alloc((size_t)NN * DH * 2);
    ushort* Wt     = (ushort*)alloc((size_t)4 * DH * DH * 2);
    int*    rowptr = (int*)alloc((NN + 1) * 4);
    int*    cursor = (int*)alloc(NN * 4);
    int*    csr    = (int*)alloc((NE + NN) * 4);
    float*  asrc   = (float*)alloc(NN * 4);
    float*  adst   = (float*)alloc(NN * 4);
    int*    deg    = (int*)alloc(NN * 4);
    int*    bsum   = (int*)alloc(64 * 4);
    int*    bbase  = (int*)alloc(64 * 4);
    float*  gsum   = (float*)alloc(NG * DH * 4);   // gsum+gcnt adjacent
    int*    gcnt   = (int*)alloc(NG * 4);

    hipMemsetAsync(deg, 0, NN * 4, stream);
    hipMemsetAsync(gsum, 0, NG * DH * 4 + 256, stream);  // covers gcnt too

    k_hist<<<(NE + 255) / 256, 256, 0, stream>>>(ei, deg);
    k_bsum<<<NSCB, 256, 0, stream>>>(deg, bsum);
    k_base<<<1, 64, 0, stream>>>(bsum, bbase, rowptr);
    k_apply<<<NSCB, 256, 0, stream>>>(deg, bbase, rowptr, cursor);
    k_scatter<<<(NE + NN + 255) / 256, 256, 0, stream>>>(ei, cursor, csr);
    k_wt<<<4 * DH * DH / 256, 256, 0, stream>>>(W0, Wc, Wt);

    const int NWAVE = NN / 16;                       // 3125
    const int GEMMB = (NWAVE + 3) / 4;               // 782 blocks of 4 waves

    k_gemm_mfma<true><<<GEMMB, 256, 0, stream>>>(x, Wt, b0, hB, 1);

    for (int l = 0; l < 3; ++l) {
        k_gemm_mfma<false><<<GEMMB, 256, 0, stream>>>(hB, Wt + (size_t)(l + 1) * DH * DH,
                                                      nullptr, hA, 0);
        k_dots<<<(NN + 3) / 4, 256, 0, stream>>>(hA, att_src + l * DH, att_dst + l * DH,
                                                 asrc, adst);
        k_aggr<<<(NN + 3) / 4, 256, 0, stream>>>(hA, asrc, adst, rowptr, csr,
                                                 bc + l * DH, hB);
    }

    k_pool<<<(NN + 63) / 64, 128, 0, stream>>>(hB, batch, gsum, gcnt);
    k_final<<<1, NG * 10, 0, stream>>>(gsum, gcnt, W1, b1, out);
}

// Round 6
// 445.503 us; speedup vs baseline: 1.6635x; 1.2185x over previous
//
#include <hip/hip_runtime.h>
#include <hip/hip_bf16.h>

#define NN 50000
#define NE 800000
#define NG 64
#define DH 128

#define SCB 4096                         // scan elements per block
#define NSCB ((NN + SCB - 1) / SCB)      // 13

typedef __bf16 bfx8 __attribute__((ext_vector_type(8)));
typedef float  f32x4 __attribute__((ext_vector_type(4)));

__device__ __forceinline__ ushort f2b(float f) {        // fp32 -> bf16 RNE
    unsigned b = __float_as_uint(f);
    b += 0x7fff + ((b >> 16) & 1);
    return (ushort)(b >> 16);
}
__device__ __forceinline__ float b2f(ushort s) {
    return __uint_as_float((unsigned)s << 16);
}
__device__ __forceinline__ float lo16(unsigned u) { return __uint_as_float(u << 16); }
__device__ __forceinline__ float hi16(unsigned u) { return __uint_as_float(u & 0xffff0000u); }
__device__ __forceinline__ unsigned pk2(float a, float b) {
    return (unsigned)f2b(a) | ((unsigned)f2b(b) << 16);
}

// ---------------- CSR build ----------------
__global__ void k_hist(const int* __restrict__ ei, int* __restrict__ deg) {
    int i = blockIdx.x * blockDim.x + threadIdx.x;
    if (i < NE) atomicAdd(&deg[ei[NE + i]], 1);
}

__launch_bounds__(256)
__global__ void k_bsum(const int* __restrict__ deg, int* __restrict__ bsum) {
    int t = threadIdx.x;
    int base = blockIdx.x * SCB + t * 16;
    int s = 0;
    #pragma unroll
    for (int j = 0; j < 16; ++j) {
        int i = base + j;
        if (i < NN) s += deg[i] + 1;     // +1 = self loop
    }
    #pragma unroll
    for (int off = 32; off; off >>= 1) s += __shfl_down(s, off);
    __shared__ int ws[4];
    if ((t & 63) == 0) ws[t >> 6] = s;
    __syncthreads();
    if (t == 0) bsum[blockIdx.x] = ws[0] + ws[1] + ws[2] + ws[3];
}

__global__ void k_base(const int* __restrict__ bsum, int* __restrict__ bbase,
                       int* __restrict__ rowptr) {
    int t = threadIdx.x;                 // 64 threads
    int orig = (t < NSCB) ? bsum[t] : 0;
    int v = orig;
    #pragma unroll
    for (int off = 1; off < 64; off <<= 1) {
        int u = __shfl_up(v, off);
        if (t >= off) v += u;
    }
    if (t < NSCB) bbase[t] = v - orig;   // exclusive
    if (t == 63) rowptr[NN] = v;         // grand total (= NE + NN)
}

__launch_bounds__(256)
__global__ void k_apply(const int* __restrict__ deg, const int* __restrict__ bbase,
                        int* __restrict__ rowptr, int* __restrict__ cursor) {
    int t = threadIdx.x;
    int base = blockIdx.x * SCB + t * 16;
    int v[16];
    int s = 0;
    #pragma unroll
    for (int j = 0; j < 16; ++j) {
        int i = base + j;
        v[j] = (i < NN) ? (deg[i] + 1) : 0;
        s += v[j];
    }
    int inc = s;
    #pragma unroll
    for (int off = 1; off < 64; off <<= 1) {
        int u = __shfl_up(inc, off);
        if ((t & 63) >= off) inc += u;
    }
    __shared__ int wsum[4];
    if ((t & 63) == 63) wsum[t >> 6] = inc;
    __syncthreads();
    int w = t >> 6;
    int woff = 0;
    #pragma unroll
    for (int k = 0; k < 4; ++k) if (k < w) woff += wsum[k];
    int run = inc - s + woff + bbase[blockIdx.x];
    #pragma unroll
    for (int j = 0; j < 16; ++j) {
        int i = base + j;
        if (i < NN) { rowptr[i] = run; cursor[i] = run; }
        run += v[j];
    }
}

__global__ void k_scatter(const int* __restrict__ ei, int* __restrict__ cursor,
                          int* __restrict__ csr) {
    int i = blockIdx.x * blockDim.x + threadIdx.x;
    if (i < NE) {
        int d = ei[NE + i];
        int p = atomicAdd(&cursor[d], 1);
        csr[p] = ei[i];
    } else if (i < NE + NN) {
        int n = i - NE;
        int p = atomicAdd(&cursor[n], 1);
        csr[p] = n;
    }
}

// ---------------- weight transpose+convert: Wt[n][k] bf16 ----------------
__global__ void k_wt(const float* __restrict__ W0, const float* __restrict__ Wc,
                     ushort* __restrict__ Wt) {
    int i = blockIdx.x * 256 + threadIdx.x;   // 0 .. 4*16384-1
    int m = i >> 14;
    int r = i & 16383;
    int k = r >> 7, n = r & 127;
    const float* src = (m == 0) ? W0 : (Wc + (size_t)(m - 1) * DH * DH);
    Wt[(size_t)m * DH * DH + n * DH + k] = f2b(src[r]);
}

// ---------------- MFMA GEMM (+ fused attention dots) ----------------------
// C[M,128] = A[M,128] @ W (Wt = W^T bf16). One wave per 16 rows, no LDS.
// D layout: col=lane&15, row=quad*4+reg (verified m89).
// DOTS: asrc/adst computed from fp32 accumulators in the epilogue.
template<bool AF32, bool DOTS>
__launch_bounds__(256)
__global__ void k_gemm_mfma(const void* __restrict__ Av, const ushort* __restrict__ Wt,
                            const float* __restrict__ bias, ushort* __restrict__ C,
                            int relu, const float* __restrict__ avs,
                            const float* __restrict__ avd,
                            float* __restrict__ asrc, float* __restrict__ adst) {
    int wid = (blockIdx.x * blockDim.x + threadIdx.x) >> 6;
    int lane = threadIdx.x & 63;
    int row0 = wid * 16;
    if (row0 >= NN) return;
    int mrow = lane & 15;
    int quad = lane >> 4;
    int arow = row0 + mrow;

    f32x4 acc[8];
    #pragma unroll
    for (int t = 0; t < 8; ++t)
        #pragma unroll
        for (int r = 0; r < 4; ++r) acc[t][r] = 0.f;

    #pragma unroll
    for (int ks = 0; ks < 4; ++ks) {
        int k0 = ks * 32 + quad * 8;
        bfx8 a;
        if (AF32) {
            const float* ap = (const float*)Av + (size_t)arow * DH + k0;
            union { ushort s[8]; bfx8 v; } u;
            #pragma unroll
            for (int j = 0; j < 8; ++j) u.s[j] = f2b(ap[j]);
            a = u.v;
        } else {
            a = *(const bfx8*)((const ushort*)Av + (size_t)arow * DH + k0);
        }
        #pragma unroll
        for (int t = 0; t < 8; ++t) {
            bfx8 b = *(const bfx8*)(Wt + (size_t)(t * 16 + mrow) * DH + k0);
            acc[t] = __builtin_amdgcn_mfma_f32_16x16x32_bf16(a, b, acc[t], 0, 0, 0);
        }
    }

    int orow = row0 + quad * 4;
    #pragma unroll
    for (int t = 0; t < 8; ++t) {
        int col = t * 16 + mrow;
        float bv = bias ? bias[col] : 0.f;
        #pragma unroll
        for (int r = 0; r < 4; ++r) {
            float v = acc[t][r] + bv;
            if (relu) v = fmaxf(v, 0.f);
            C[(size_t)(orow + r) * DH + col] = f2b(v);
        }
    }

    if (DOTS) {
        float av[8], dv[8];
        #pragma unroll
        for (int t = 0; t < 8; ++t) {
            av[t] = avs[t * 16 + mrow];
            dv[t] = avd[t * 16 + mrow];
        }
        #pragma unroll
        for (int r = 0; r < 4; ++r) {
            float ps = 0.f, pd = 0.f;
            #pragma unroll
            for (int t = 0; t < 8; ++t) {
                ps += acc[t][r] * av[t];
                pd += acc[t][r] * dv[t];
            }
            #pragma unroll
            for (int off = 1; off < 16; off <<= 1) {
                ps += __shfl_xor(ps, off);
                pd += __shfl_xor(pd, off);
            }
            if (mrow == 0) {
                asrc[orow + r] = ps;
                adst[orow + r] = pd;
            }
        }
    }
}

// ---------------- fused segment softmax + weighted aggregate (bf16 h) -------
// one wave per node; fast path (deg<=64): single-chunk logits, 4 edges/step
// aggregation with dwordx4 gathers (lane = 4 edge-groups x 16 feature-blocks).
__launch_bounds__(256)
__global__ void k_aggr(const ushort* __restrict__ h, const float* __restrict__ asrc,
                       const float* __restrict__ adst, const int* __restrict__ rowptr,
                       const int* __restrict__ csr, const float* __restrict__ bias,
                       ushort* __restrict__ hout) {
    int wid = (blockIdx.x * blockDim.x + threadIdx.x) >> 6;
    int lane = threadIdx.x & 63;
    if (wid >= NN) return;
    int beg = rowptr[wid], end = rowptr[wid + 1];
    int cnt = end - beg;
    float ad = adst[wid];

    if (cnt <= 64) {
        int s = 0;
        float e = -1e30f;
        if (lane < cnt) {
            s = csr[beg + lane];
            float t = asrc[s] + ad;
            e = fmaxf(t, 0.f) + 0.2f * fminf(t, 0.f);
        }
        float m = e;
        #pragma unroll
        for (int off = 32; off; off >>= 1) m = fmaxf(m, __shfl_xor(m, off));
        float w = (lane < cnt) ? __expf(e - m) : 0.f;
        float dsum = w;
        #pragma unroll
        for (int off = 32; off; off >>= 1) dsum += __shfl_xor(dsum, off);

        int g = lane >> 4, fidx = lane & 15;
        float acc[8];
        #pragma unroll
        for (int k = 0; k < 8; ++k) acc[k] = 0.f;

        int steps = (cnt + 3) >> 2;
        const uint4* hp = (const uint4*)h;
        for (int j = 0; j < steps; ++j) {
            int eidx = j * 4 + g;
            float wj = __shfl(w, eidx);
            int   sj = __shfl(s, eidx);
            if (eidx < cnt) {
                uint4 u = hp[(size_t)sj * 16 + fidx];
                acc[0] += wj * lo16(u.x); acc[1] += wj * hi16(u.x);
                acc[2] += wj * lo16(u.y); acc[3] += wj * hi16(u.y);
                acc[4] += wj * lo16(u.z); acc[5] += wj * hi16(u.z);
                acc[6] += wj * lo16(u.w); acc[7] += wj * hi16(u.w);
            }
        }
        #pragma unroll
        for (int k = 0; k < 8; ++k) {
            acc[k] += __shfl_xor(acc[k], 16);
            acc[k] += __shfl_xor(acc[k], 32);
        }
        if (g == 0) {
            float inv = 1.f / (dsum + 1e-16f);
            const float4* bp = (const float4*)bias;
            float4 b0 = bp[fidx * 2], b1 = bp[fidx * 2 + 1];
            uint4 o;
            o.x = pk2(fmaxf(acc[0] * inv + b0.x, 0.f), fmaxf(acc[1] * inv + b0.y, 0.f));
            o.y = pk2(fmaxf(acc[2] * inv + b0.z, 0.f), fmaxf(acc[3] * inv + b0.w, 0.f));
            o.z = pk2(fmaxf(acc[4] * inv + b1.x, 0.f), fmaxf(acc[5] * inv + b1.y, 0.f));
            o.w = pk2(fmaxf(acc[6] * inv + b1.z, 0.f), fmaxf(acc[7] * inv + b1.w, 0.f));
            ((uint4*)hout)[(size_t)wid * 16 + fidx] = o;
        }
        return;
    }

    // generic fallback (deg > 64) — rare/never with this data
    float m = -1e30f;
    for (int i0 = beg; i0 < end; i0 += 64) {
        int i = i0 + lane;
        float e = -1e30f;
        if (i < end) {
            int s = csr[i];
            float t = asrc[s] + ad;
            e = fmaxf(t, 0.f) + 0.2f * fminf(t, 0.f);
        }
        m = fmaxf(m, e);
    }
    #pragma unroll
    for (int off = 32; off; off >>= 1) m = fmaxf(m, __shfl_xor(m, off));

    float accx = 0.f, accy = 0.f, dsum = 0.f;
    for (int i0 = beg; i0 < end; i0 += 64) {
        int i = i0 + lane;
        int s = 0; float w = 0.f;
        if (i < end) {
            s = csr[i];
            float t = asrc[s] + ad;
            float e = fmaxf(t, 0.f) + 0.2f * fminf(t, 0.f);
            w = __expf(e - m);
        }
        dsum += w;
        int cl = min(64, end - i0);
        for (int j = 0; j < cl; ++j) {
            int   sj = __shfl(s, j);
            float wj = __shfl(w, j);
            unsigned u = *(const unsigned*)(h + (size_t)sj * DH + lane * 2);
            accx += wj * lo16(u);
            accy += wj * hi16(u);
        }
    }
    #pragma unroll
    for (int off = 32; off; off >>= 1) dsum += __shfl_xor(dsum, off);

    float inv = 1.f / (dsum + 1e-16f);
    float ox = fmaxf(accx * inv + bias[lane * 2], 0.f);
    float oy = fmaxf(accy * inv + bias[lane * 2 + 1], 0.f);
    *(unsigned*)(hout + (size_t)wid * DH + lane * 2) = pk2(ox, oy);
}

// ---------------- mean pool (batch sorted, bf16 h) ----------------
__launch_bounds__(128)
__global__ void k_pool(const ushort* __restrict__ h, const int* __restrict__ batch,
                       float* __restrict__ gsum, int* __restrict__ gcnt) {
    int f = threadIdx.x;
    int n0 = blockIdx.x * 64;
    int n1 = min(n0 + 64, NN);
    float acc = 0.f; int run = 0;
    int gcur = batch[n0];
    for (int nd = n0; nd < n1; ++nd) {
        int g = batch[nd];
        if (g != gcur) {
            atomicAdd(&gsum[gcur * DH + f], acc);
            if (f == 0) atomicAdd(&gcnt[gcur], run);
            acc = 0.f; run = 0; gcur = g;
        }
        acc += b2f(h[(size_t)nd * DH + f]);
        run += 1;
    }
    atomicAdd(&gsum[gcur * DH + f], acc);
    if (f == 0) atomicAdd(&gcnt[gcur], run);
}

// ---------------- final linear [64,128]@[128,10] -> fp32 out ----------------
__global__ void k_final(const float* __restrict__ gsum, const int* __restrict__ gcnt,
                        const float* __restrict__ W1, const float* __restrict__ b1,
                        float* __restrict__ out) {
    int t = threadIdx.x;
    if (t >= NG * 10) return;
    int g = t / 10, o = t % 10;
    float inv = 1.f / fmaxf((float)gcnt[g], 1.f);
    float acc = 0.f;
    for (int f = 0; f < DH; ++f) acc += gsum[g * DH + f] * W1[f * 10 + o];
    out[t] = acc * inv + b1[o];
}

extern "C" void kernel_launch(void* const* d_in, const int* in_sizes, int n_in,
                              void* d_out, int out_size, void* d_ws, size_t ws_size,
                              hipStream_t stream) {
    const float* x       = (const float*)d_in[0];
    const int*   ei      = (const int*)d_in[1];
    const int*   batch   = (const int*)d_in[3];
    const float* W0      = (const float*)d_in[4];
    const float* b0      = (const float*)d_in[5];
    const float* Wc      = (const float*)d_in[6];
    const float* att_src = (const float*)d_in[7];
    const float* att_dst = (const float*)d_in[8];
    const float* bc      = (const float*)d_in[9];
    const float* W1      = (const float*)d_in[10];
    const float* b1      = (const float*)d_in[11];
    float* out = (float*)d_out;

    char* ws = (char*)d_ws;
    size_t off = 0;
    auto alloc = [&](size_t bytes) {
        void* p = ws + off;
        off += (bytes + 255) & ~(size_t)255;
        return p;
    };
    ushort* hA     = (ushort*)alloc((size_t)NN * DH * 2);
    ushort* hB     = (ushort*)alloc((size_t)NN * DH * 2);
    ushort* Wt     = (ushort*)alloc((size_t)4 * DH * DH * 2);
    int*    rowptr = (int*)alloc((NN + 1) * 4);
    int*    cursor = (int*)alloc(NN * 4);
    int*    csr    = (int*)alloc((NE + NN) * 4);
    float*  asrc   = (float*)alloc(NN * 4);
    float*  adst   = (float*)alloc(NN * 4);
    int*    deg    = (int*)alloc(NN * 4);
    int*    bsum   = (int*)alloc(64 * 4);
    int*    bbase  = (int*)alloc(64 * 4);
    float*  gsum   = (float*)alloc(NG * DH * 4);   // gsum+gcnt adjacent
    int*    gcnt   = (int*)alloc(NG * 4);

    hipMemsetAsync(deg, 0, NN * 4, stream);
    hipMemsetAsync(gsum, 0, NG * DH * 4 + 256, stream);  // covers gcnt too

    k_hist<<<(NE + 255) / 256, 256, 0, stream>>>(ei, deg);
    k_bsum<<<NSCB, 256, 0, stream>>>(deg, bsum);
    k_base<<<1, 64, 0, stream>>>(bsum, bbase, rowptr);
    k_apply<<<NSCB, 256, 0, stream>>>(deg, bbase, rowptr, cursor);
    k_scatter<<<(NE + NN + 255) / 256, 256, 0, stream>>>(ei, cursor, csr);
    k_wt<<<4 * DH * DH / 256, 256, 0, stream>>>(W0, Wc, Wt);

    const int NWAVE = NN / 16;                       // 3125
    const int GEMMB = (NWAVE + 3) / 4;               // 782 blocks of 4 waves

    k_gemm_mfma<true, false><<<GEMMB, 256, 0, stream>>>(
        x, Wt, b0, hB, 1, nullptr, nullptr, nullptr, nullptr);

    for (int l = 0; l < 3; ++l) {
        k_gemm_mfma<false, true><<<GEMMB, 256, 0, stream>>>(
            hB, Wt + (size_t)(l + 1) * DH * DH, nullptr, hA, 0,
            att_src + l * DH, att_dst + l * DH, asrc, adst);
        k_aggr<<<(NN + 3) / 4, 256, 0, stream>>>(hA, asrc, adst, rowptr, csr,
                                                 bc + l * DH, hB);
    }

    k_pool<<<(NN + 63) / 64, 128, 0, stream>>>(hB, batch, gsum, gcnt);
    k_final<<<1, NG * 10, 0, stream>>>(gsum, gcnt, W1, b1, out);
}

// Round 7
// 400.615 us; speedup vs baseline: 1.8499x; 1.1120x over previous
//
#include <hip/hip_runtime.h>
#include <hip/hip_bf16.h>

#define NN 50000
#define NE 800000
#define NG 64
#define DH 128

#define SCB 4096                         // scan elements per block
#define NSCB ((NN + SCB - 1) / SCB)      // 13
#define NPB 256                          // nodes per bucket
#define NBK ((NN + NPB - 1) / NPB)       // 196 buckets
#define EPB 4096                         // edges per partition block
#define NPBLK ((NE + EPB - 1) / EPB)     // 196

typedef __bf16 bfx8 __attribute__((ext_vector_type(8)));
typedef float  f32x4 __attribute__((ext_vector_type(4)));

__device__ __forceinline__ ushort f2b(float f) {        // fp32 -> bf16 RNE
    unsigned b = __float_as_uint(f);
    b += 0x7fff + ((b >> 16) & 1);
    return (ushort)(b >> 16);
}
__device__ __forceinline__ float b2f(ushort s) {
    return __uint_as_float((unsigned)s << 16);
}
__device__ __forceinline__ float lo16(unsigned u) { return __uint_as_float(u << 16); }
__device__ __forceinline__ float hi16(unsigned u) { return __uint_as_float(u & 0xffff0000u); }
__device__ __forceinline__ unsigned pk2(float a, float b) {
    return (unsigned)f2b(a) | ((unsigned)f2b(b) << 16);
}

// ---------------- degree histogram ----------------
__global__ void k_hist(const int* __restrict__ ei, int* __restrict__ deg) {
    int i = blockIdx.x * blockDim.x + threadIdx.x;
    if (i < NE) atomicAdd(&deg[ei[NE + i]], 1);
}

// ---------------- padded-segment scan: pstart[i] = sum align4(deg+1) --------
__launch_bounds__(256)
__global__ void k_bsum(const int* __restrict__ deg, int* __restrict__ bsum) {
    int t = threadIdx.x;
    int base = blockIdx.x * SCB + t * 16;
    int s = 0;
    #pragma unroll
    for (int j = 0; j < 16; ++j) {
        int i = base + j;
        if (i < NN) s += (deg[i] + 4) & ~3;     // align4(deg+1)
    }
    #pragma unroll
    for (int off = 32; off; off >>= 1) s += __shfl_down(s, off);
    __shared__ int ws[4];
    if ((t & 63) == 0) ws[t >> 6] = s;
    __syncthreads();
    if (t == 0) bsum[blockIdx.x] = ws[0] + ws[1] + ws[2] + ws[3];
}

__global__ void k_base(const int* __restrict__ bsum, int* __restrict__ bbase,
                       int* __restrict__ pstart) {
    int t = threadIdx.x;                 // 64 threads
    int orig = (t < NSCB) ? bsum[t] : 0;
    int v = orig;
    #pragma unroll
    for (int off = 1; off < 64; off <<= 1) {
        int u = __shfl_up(v, off);
        if (t >= off) v += u;
    }
    if (t < NSCB) bbase[t] = v - orig;   // exclusive
    if (t == 63) pstart[NN] = v;         // padded grand total
}

__launch_bounds__(256)
__global__ void k_apply(const int* __restrict__ deg, const int* __restrict__ bbase,
                        int* __restrict__ pstart) {
    int t = threadIdx.x;
    int base = blockIdx.x * SCB + t * 16;
    int v[16];
    int s = 0;
    #pragma unroll
    for (int j = 0; j < 16; ++j) {
        int i = base + j;
        v[j] = (i < NN) ? ((deg[i] + 4) & ~3) : 0;
        s += v[j];
    }
    int inc = s;
    #pragma unroll
    for (int off = 1; off < 64; off <<= 1) {
        int u = __shfl_up(inc, off);
        if ((t & 63) >= off) inc += u;
    }
    __shared__ int wsum[4];
    if ((t & 63) == 63) wsum[t >> 6] = inc;
    __syncthreads();
    int w = t >> 6;
    int woff = 0;
    #pragma unroll
    for (int k = 0; k < 4; ++k) if (k < w) woff += wsum[k];
    int run = inc - s + woff + bbase[blockIdx.x];
    #pragma unroll
    for (int j = 0; j < 16; ++j) {
        int i = base + j;
        if (i < NN) pstart[i] = run;
        run += v[j];
    }
}

// ---------------- bucket edge counts + scan ----------------
__global__ void k_bksum(const int* __restrict__ deg, int* __restrict__ bsize) {
    int b = blockIdx.x, t = threadIdx.x;
    int n = b * NPB + t;
    int v = (n < NN) ? deg[n] : 0;
    #pragma unroll
    for (int off = 32; off; off >>= 1) v += __shfl_down(v, off);
    __shared__ int ws[4];
    if ((t & 63) == 0) ws[t >> 6] = v;
    __syncthreads();
    if (t == 0) bsize[b] = ws[0] + ws[1] + ws[2] + ws[3];
}

__global__ void k_bscan(const int* __restrict__ bsize, int* __restrict__ tstart,
                        int* __restrict__ tcur) {
    __shared__ int sm[256];
    int t = threadIdx.x;
    int v = (t < NBK) ? bsize[t] : 0;
    sm[t] = v;
    __syncthreads();
    for (int off = 1; off < 256; off <<= 1) {
        int u = (t >= off) ? sm[t - off] : 0;
        __syncthreads();
        sm[t] += u;
        __syncthreads();
    }
    int excl = sm[t] - v;
    if (t < NBK) { tstart[t] = excl; tcur[t] = excl; }
    if (t == NBK - 1) tstart[NBK] = sm[t];
}

// ---------------- partition edges into dst-buckets (coalesced runs) --------
__launch_bounds__(256)
__global__ void k_part(const int* __restrict__ ei, int* __restrict__ tcur,
                       unsigned* __restrict__ tmp) {
    __shared__ int cnt[NBK], base[NBK], lcur[NBK];
    int t = threadIdx.x;
    for (int i = t; i < NBK; i += 256) cnt[i] = 0;
    __syncthreads();
    int e0 = blockIdx.x * EPB;
    #pragma unroll
    for (int j = 0; j < 16; ++j) {
        int e = e0 + j * 256 + t;
        if (e < NE) atomicAdd(&cnt[ei[NE + e] >> 8], 1);
    }
    __syncthreads();
    for (int i = t; i < NBK; i += 256) {
        base[i] = cnt[i] ? atomicAdd(&tcur[i], cnt[i]) : 0;
        lcur[i] = 0;
    }
    __syncthreads();
    #pragma unroll
    for (int j = 0; j < 16; ++j) {
        int e = e0 + j * 256 + t;
        if (e < NE) {
            int d = ei[NE + e], s = ei[e];
            int b = d >> 8;
            int r = atomicAdd(&lcur[b], 1);
            tmp[base[b] + r] = ((unsigned)d << 16) | (unsigned)s;
        }
    }
}

// ---------------- build csr per bucket, LDS-staged, sequential writes ------
__launch_bounds__(256)
__global__ void k_build(const unsigned* __restrict__ tmp, const int* __restrict__ tstart,
                        const int* __restrict__ pstart, ushort* __restrict__ csr) {
    __shared__ ushort buf[8192];
    __shared__ int lcur[NPB];
    int b = blockIdx.x, t = threadIdx.x;
    int n0 = b * NPB, n1 = min(n0 + NPB, NN), nodes = n1 - n0;
    int r0 = pstart[n0], r1 = pstart[n1], S = r1 - r0;   // multiple of 4
    int t0 = tstart[b], t1 = tstart[b + 1];

    if (S <= 8192) {
        for (int i = t; i < (S >> 1); i += 256) ((unsigned*)buf)[i] = 0;
        __syncthreads();
        if (t < nodes) {
            int p = pstart[n0 + t] - r0;
            lcur[t] = p + 1;
            buf[p] = (ushort)(n0 + t);               // self-loop first
        }
        __syncthreads();
        for (int e = t0 + t; e < t1; e += 256) {
            unsigned u = tmp[e];
            int d = (int)(u >> 16) - n0;
            int slot = atomicAdd(&lcur[d], 1);
            buf[slot] = (ushort)(u & 0xffffu);
        }
        __syncthreads();
        unsigned* dst = (unsigned*)(csr + r0);
        for (int i = t; i < (S >> 1); i += 256) dst[i] = ((unsigned*)buf)[i];
    } else {
        // fallback (never with this data): direct global writes
        for (int i = t; i < S; i += 256) csr[r0 + i] = 0;
        __syncthreads();
        if (t < nodes) {
            int p = pstart[n0 + t];
            lcur[t] = p + 1;
            csr[p] = (ushort)(n0 + t);
        }
        __syncthreads();
        for (int e = t0 + t; e < t1; e += 256) {
            unsigned u = tmp[e];
            int d = (int)(u >> 16) - n0;
            int slot = atomicAdd(&lcur[d], 1);
            csr[slot] = (ushort)(u & 0xffffu);
        }
    }
}

// ---------------- weight transpose+convert: Wt[n][k] bf16 ----------------
__global__ void k_wt(const float* __restrict__ W0, const float* __restrict__ Wc,
                     ushort* __restrict__ Wt) {
    int i = blockIdx.x * 256 + threadIdx.x;   // 0 .. 4*16384-1
    int m = i >> 14;
    int r = i & 16383;
    int k = r >> 7, n = r & 127;
    const float* src = (m == 0) ? W0 : (Wc + (size_t)(m - 1) * DH * DH);
    Wt[(size_t)m * DH * DH + n * DH + k] = f2b(src[r]);
}

// ---------------- MFMA GEMM (+ fused attention dots) ----------------------
template<bool AF32, bool DOTS>
__launch_bounds__(256)
__global__ void k_gemm_mfma(const void* __restrict__ Av, const ushort* __restrict__ Wt,
                            const float* __restrict__ bias, ushort* __restrict__ C,
                            int relu, const float* __restrict__ avs,
                            const float* __restrict__ avd,
                            float* __restrict__ asrc, float* __restrict__ adst) {
    int wid = (blockIdx.x * blockDim.x + threadIdx.x) >> 6;
    int lane = threadIdx.x & 63;
    int row0 = wid * 16;
    if (row0 >= NN) return;
    int mrow = lane & 15;
    int quad = lane >> 4;
    int arow = row0 + mrow;

    f32x4 acc[8];
    #pragma unroll
    for (int t = 0; t < 8; ++t)
        #pragma unroll
        for (int r = 0; r < 4; ++r) acc[t][r] = 0.f;

    #pragma unroll
    for (int ks = 0; ks < 4; ++ks) {
        int k0 = ks * 32 + quad * 8;
        bfx8 a;
        if (AF32) {
            const float* ap = (const float*)Av + (size_t)arow * DH + k0;
            union { ushort s[8]; bfx8 v; } u;
            #pragma unroll
            for (int j = 0; j < 8; ++j) u.s[j] = f2b(ap[j]);
            a = u.v;
        } else {
            a = *(const bfx8*)((const ushort*)Av + (size_t)arow * DH + k0);
        }
        #pragma unroll
        for (int t = 0; t < 8; ++t) {
            bfx8 b = *(const bfx8*)(Wt + (size_t)(t * 16 + mrow) * DH + k0);
            acc[t] = __builtin_amdgcn_mfma_f32_16x16x32_bf16(a, b, acc[t], 0, 0, 0);
        }
    }

    int orow = row0 + quad * 4;
    #pragma unroll
    for (int t = 0; t < 8; ++t) {
        int col = t * 16 + mrow;
        float bv = bias ? bias[col] : 0.f;
        #pragma unroll
        for (int r = 0; r < 4; ++r) {
            float v = acc[t][r] + bv;
            if (relu) v = fmaxf(v, 0.f);
            C[(size_t)(orow + r) * DH + col] = f2b(v);
        }
    }

    if (DOTS) {
        float av[8], dv[8];
        #pragma unroll
        for (int t = 0; t < 8; ++t) {
            av[t] = avs[t * 16 + mrow];
            dv[t] = avd[t * 16 + mrow];
        }
        #pragma unroll
        for (int r = 0; r < 4; ++r) {
            float ps = 0.f, pd = 0.f;
            #pragma unroll
            for (int t = 0; t < 8; ++t) {
                ps += acc[t][r] * av[t];
                pd += acc[t][r] * dv[t];
            }
            #pragma unroll
            for (int off = 1; off < 16; off <<= 1) {
                ps += __shfl_xor(ps, off);
                pd += __shfl_xor(pd, off);
            }
            if (mrow == 0) {
                asrc[orow + r] = ps;
                adst[orow + r] = pd;
            }
        }
    }
}

// ---------------- fused segment softmax + weighted aggregate (bf16 h) -------
// one wave per node; padded segments (x4, zero-pad) -> unguarded 2x-unrolled
// dwordx4 gathers, 4 edges/step, lane = (edge-group g, feature-block fidx).
__launch_bounds__(256)
__global__ void k_aggr(const ushort* __restrict__ h, const float* __restrict__ asrc,
                       const float* __restrict__ adst, const int* __restrict__ pstart,
                       const int* __restrict__ deg, const ushort* __restrict__ csr,
                       const float* __restrict__ bias, ushort* __restrict__ hout) {
    int wid = (blockIdx.x * blockDim.x + threadIdx.x) >> 6;
    int lane = threadIdx.x & 63;
    if (wid >= NN) return;
    int start = pstart[wid];
    int cnt = deg[wid] + 1;
    float ad = adst[wid];

    if (cnt <= 64) {
        int s = csr[start + lane];               // pads are 0 (valid index)
        float e = -1e30f;
        if (lane < cnt) {
            float t = asrc[s] + ad;
            e = fmaxf(t, 0.f) + 0.2f * fminf(t, 0.f);
        }
        float m = e;
        #pragma unroll
        for (int off = 32; off; off >>= 1) m = fmaxf(m, __shfl_xor(m, off));
        float w = (lane < cnt) ? __expf(e - m) : 0.f;
        float dsum = w;
        #pragma unroll
        for (int off = 32; off; off >>= 1) dsum += __shfl_xor(dsum, off);

        int g = lane >> 4, fidx = lane & 15;
        float acc[8];
        #pragma unroll
        for (int k = 0; k < 8; ++k) acc[k] = 0.f;

        int steps = (cnt + 3) >> 2;
        const uint4* hp = (const uint4*)h;
        int j = 0;
        for (; j + 1 < steps; j += 2) {
            int e0 = j * 4 + g, e1 = e0 + 4;
            float w0 = __shfl(w, e0), w1 = __shfl(w, e1);
            int   s0 = __shfl(s, e0), s1 = __shfl(s, e1);
            uint4 u0 = hp[(size_t)s0 * 16 + fidx];
            uint4 u1 = hp[(size_t)s1 * 16 + fidx];
            acc[0] += w0 * lo16(u0.x); acc[1] += w0 * hi16(u0.x);
            acc[2] += w0 * lo16(u0.y); acc[3] += w0 * hi16(u0.y);
            acc[4] += w0 * lo16(u0.z); acc[5] += w0 * hi16(u0.z);
            acc[6] += w0 * lo16(u0.w); acc[7] += w0 * hi16(u0.w);
            acc[0] += w1 * lo16(u1.x); acc[1] += w1 * hi16(u1.x);
            acc[2] += w1 * lo16(u1.y); acc[3] += w1 * hi16(u1.y);
            acc[4] += w1 * lo16(u1.z); acc[5] += w1 * hi16(u1.z);
            acc[6] += w1 * lo16(u1.w); acc[7] += w1 * hi16(u1.w);
        }
        if (j < steps) {
            int e0 = j * 4 + g;
            float w0 = __shfl(w, e0);
            int   s0 = __shfl(s, e0);
            uint4 u0 = hp[(size_t)s0 * 16 + fidx];
            acc[0] += w0 * lo16(u0.x); acc[1] += w0 * hi16(u0.x);
            acc[2] += w0 * lo16(u0.y); acc[3] += w0 * hi16(u0.y);
            acc[4] += w0 * lo16(u0.z); acc[5] += w0 * hi16(u0.z);
            acc[6] += w0 * lo16(u0.w); acc[7] += w0 * hi16(u0.w);
        }
        #pragma unroll
        for (int k = 0; k < 8; ++k) {
            acc[k] += __shfl_xor(acc[k], 16);
            acc[k] += __shfl_xor(acc[k], 32);
        }
        if (g == 0) {
            float inv = 1.f / (dsum + 1e-16f);
            const float4* bp = (const float4*)bias;
            float4 b0 = bp[fidx * 2], b1 = bp[fidx * 2 + 1];
            uint4 o;
            o.x = pk2(fmaxf(acc[0] * inv + b0.x, 0.f), fmaxf(acc[1] * inv + b0.y, 0.f));
            o.y = pk2(fmaxf(acc[2] * inv + b0.z, 0.f), fmaxf(acc[3] * inv + b0.w, 0.f));
            o.z = pk2(fmaxf(acc[4] * inv + b1.x, 0.f), fmaxf(acc[5] * inv + b1.y, 0.f));
            o.w = pk2(fmaxf(acc[6] * inv + b1.z, 0.f), fmaxf(acc[7] * inv + b1.w, 0.f));
            ((uint4*)hout)[(size_t)wid * 16 + fidx] = o;
        }
        return;
    }

    // generic fallback (deg > 64) — never with this data
    float m = -1e30f;
    for (int i0 = start; i0 < start + cnt; i0 += 64) {
        int i = i0 + lane;
        float e = -1e30f;
        if (i < start + cnt) {
            int s = csr[i];
            float t = asrc[s] + ad;
            e = fmaxf(t, 0.f) + 0.2f * fminf(t, 0.f);
        }
        m = fmaxf(m, e);
    }
    #pragma unroll
    for (int off = 32; off; off >>= 1) m = fmaxf(m, __shfl_xor(m, off));

    float accx = 0.f, accy = 0.f, dsum = 0.f;
    for (int i0 = start; i0 < start + cnt; i0 += 64) {
        int i = i0 + lane;
        int s = 0; float w = 0.f;
        if (i < start + cnt) {
            s = csr[i];
            float t = asrc[s] + ad;
            float e = fmaxf(t, 0.f) + 0.2f * fminf(t, 0.f);
            w = __expf(e - m);
        }
        dsum += w;
        int cl = min(64, start + cnt - i0);
        for (int j = 0; j < cl; ++j) {
            int   sj = __shfl(s, j);
            float wj = __shfl(w, j);
            unsigned u = *(const unsigned*)(h + (size_t)sj * DH + lane * 2);
            accx += wj * lo16(u);
            accy += wj * hi16(u);
        }
    }
    #pragma unroll
    for (int off = 32; off; off >>= 1) dsum += __shfl_xor(dsum, off);

    float inv = 1.f / (dsum + 1e-16f);
    float ox = fmaxf(accx * inv + bias[lane * 2], 0.f);
    float oy = fmaxf(accy * inv + bias[lane * 2 + 1], 0.f);
    *(unsigned*)(hout + (size_t)wid * DH + lane * 2) = pk2(ox, oy);
}

// ---------------- mean pool (batch sorted, bf16 h) ----------------
__launch_bounds__(128)
__global__ void k_pool(const ushort* __restrict__ h, const int* __restrict__ batch,
                       float* __restrict__ gsum, int* __restrict__ gcnt) {
    int f = threadIdx.x;
    int n0 = blockIdx.x * 64;
    int n1 = min(n0 + 64, NN);
    float acc = 0.f; int run = 0;
    int gcur = batch[n0];
    for (int nd = n0; nd < n1; ++nd) {
        int g = batch[nd];
        if (g != gcur) {
            atomicAdd(&gsum[gcur * DH + f], acc);
            if (f == 0) atomicAdd(&gcnt[gcur], run);
            acc = 0.f; run = 0; gcur = g;
        }
        acc += b2f(h[(size_t)nd * DH + f]);
        run += 1;
    }
    atomicAdd(&gsum[gcur * DH + f], acc);
    if (f == 0) atomicAdd(&gcnt[gcur], run);
}

// ---------------- final linear [64,128]@[128,10] -> fp32 out ----------------
__global__ void k_final(const float* __restrict__ gsum, const int* __restrict__ gcnt,
                        const float* __restrict__ W1, const float* __restrict__ b1,
                        float* __restrict__ out) {
    int t = threadIdx.x;
    if (t >= NG * 10) return;
    int g = t / 10, o = t % 10;
    float inv = 1.f / fmaxf((float)gcnt[g], 1.f);
    float acc = 0.f;
    for (int f = 0; f < DH; ++f) acc += gsum[g * DH + f] * W1[f * 10 + o];
    out[t] = acc * inv + b1[o];
}

extern "C" void kernel_launch(void* const* d_in, const int* in_sizes, int n_in,
                              void* d_out, int out_size, void* d_ws, size_t ws_size,
                              hipStream_t stream) {
    const float* x       = (const float*)d_in[0];
    const int*   ei      = (const int*)d_in[1];
    const int*   batch   = (const int*)d_in[3];
    const float* W0      = (const float*)d_in[4];
    const float* b0      = (const float*)d_in[5];
    const float* Wc      = (const float*)d_in[6];
    const float* att_src = (const float*)d_in[7];
    const float* att_dst = (const float*)d_in[8];
    const float* bc      = (const float*)d_in[9];
    const float* W1      = (const float*)d_in[10];
    const float* b1      = (const float*)d_in[11];
    float* out = (float*)d_out;

    char* ws = (char*)d_ws;
    size_t off = 0;
    auto alloc = [&](size_t bytes) {
        void* p = ws + off;
        off += (bytes + 255) & ~(size_t)255;
        return p;
    };
    ushort*   hA     = (ushort*)alloc((size_t)NN * DH * 2);
    ushort*   hB     = (ushort*)alloc((size_t)NN * DH * 2);
    ushort*   Wt     = (ushort*)alloc((size_t)4 * DH * DH * 2);
    int*      pstart = (int*)alloc((NN + 1) * 4);
    ushort*   csr    = (ushort*)alloc((size_t)(NE + 4 * NN + 64) * 2);
    unsigned* tmp    = (unsigned*)alloc((size_t)NE * 4);
    float*    asrc   = (float*)alloc(NN * 4);
    float*    adst   = (float*)alloc(NN * 4);
    int*      deg    = (int*)alloc(NN * 4);
    int*      bsum   = (int*)alloc(64 * 4);
    int*      bbase  = (int*)alloc(64 * 4);
    int*      bsize  = (int*)alloc((NBK + 1) * 4);
    int*      tstart = (int*)alloc((NBK + 1) * 4);
    int*      tcur   = (int*)alloc((NBK + 1) * 4);
    float*    gsum   = (float*)alloc(NG * DH * 4);   // gsum+gcnt adjacent
    int*      gcnt   = (int*)alloc(NG * 4);

    hipMemsetAsync(deg, 0, NN * 4, stream);
    hipMemsetAsync(gsum, 0, NG * DH * 4 + 256, stream);  // covers gcnt too

    k_hist<<<(NE + 255) / 256, 256, 0, stream>>>(ei, deg);
    k_bsum<<<NSCB, 256, 0, stream>>>(deg, bsum);
    k_base<<<1, 64, 0, stream>>>(bsum, bbase, pstart);
    k_apply<<<NSCB, 256, 0, stream>>>(deg, bbase, pstart);
    k_bksum<<<NBK, 256, 0, stream>>>(deg, bsize);
    k_bscan<<<1, 256, 0, stream>>>(bsize, tstart, tcur);
    k_part<<<NPBLK, 256, 0, stream>>>(ei, tcur, tmp);
    k_build<<<NBK, 256, 0, stream>>>(tmp, tstart, pstart, csr);
    k_wt<<<4 * DH * DH / 256, 256, 0, stream>>>(W0, Wc, Wt);

    const int NWAVE = NN / 16;                       // 3125
    const int GEMMB = (NWAVE + 3) / 4;               // 782 blocks of 4 waves

    k_gemm_mfma<true, false><<<GEMMB, 256, 0, stream>>>(
        x, Wt, b0, hB, 1, nullptr, nullptr, nullptr, nullptr);

    for (int l = 0; l < 3; ++l) {
        k_gemm_mfma<false, true><<<GEMMB, 256, 0, stream>>>(
            hB, Wt + (size_t)(l + 1) * DH * DH, nullptr, hA, 0,
            att_src + l * DH, att_dst + l * DH, asrc, adst);
        k_aggr<<<(NN + 3) / 4, 256, 0, stream>>>(hA, asrc, adst, pstart, deg, csr,
                                                 bc + l * DH, hB);
    }

    k_pool<<<(NN + 63) / 64, 128, 0, stream>>>(hB, batch, gsum, gcnt);
    k_final<<<1, NG * 10, 0, stream>>>(gsum, gcnt, W1, b1, out);
}

// Round 8
// 395.936 us; speedup vs baseline: 1.8718x; 1.0118x over previous
//
#include <hip/hip_runtime.h>
#include <hip/hip_bf16.h>

#define NN 50000
#define NE 800000
#define NG 64
#define DH 128

#define NPB 256                          // nodes per bucket
#define NBK ((NN + NPB - 1) / NPB)       // 196 buckets
#define EPB 4096                         // edges per partition block
#define NPBLK ((NE + EPB - 1) / EPB)     // 196

typedef __bf16 bfx8 __attribute__((ext_vector_type(8)));
typedef float  f32x4 __attribute__((ext_vector_type(4)));

__device__ __forceinline__ ushort f2b(float f) {        // fp32 -> bf16 RNE
    unsigned b = __float_as_uint(f);
    b += 0x7fff + ((b >> 16) & 1);
    return (ushort)(b >> 16);
}
__device__ __forceinline__ float b2f(ushort s) {
    return __uint_as_float((unsigned)s << 16);
}
__device__ __forceinline__ float lo16(unsigned u) { return __uint_as_float(u << 16); }
__device__ __forceinline__ float hi16(unsigned u) { return __uint_as_float(u & 0xffff0000u); }
__device__ __forceinline__ unsigned pk2(float a, float b) {
    return (unsigned)f2b(a) | ((unsigned)f2b(b) << 16);
}

// ---------------- degree histogram ----------------
__global__ void k_hist(const int* __restrict__ ei, int* __restrict__ deg) {
    int i = blockIdx.x * blockDim.x + threadIdx.x;
    if (i < NE) atomicAdd(&deg[ei[NE + i]], 1);
}

// ---------------- per-bucket sums: edges and padded slots ----------------
__global__ void k_sizes(const int* __restrict__ deg, int* __restrict__ bsizeE,
                        int* __restrict__ bsizeP) {
    int b = blockIdx.x, t = threadIdx.x;
    int n = b * NPB + t;
    int d = (n < NN) ? deg[n] : 0;
    int e = (n < NN) ? d : 0;
    int p = (n < NN) ? ((d + 4) & ~3) : 0;       // align4(deg+1)
    #pragma unroll
    for (int off = 32; off; off >>= 1) {
        e += __shfl_down(e, off);
        p += __shfl_down(p, off);
    }
    __shared__ int we[4], wp[4];
    if ((t & 63) == 0) { we[t >> 6] = e; wp[t >> 6] = p; }
    __syncthreads();
    if (t == 0) {
        bsizeE[b] = we[0] + we[1] + we[2] + we[3];
        bsizeP[b] = wp[0] + wp[1] + wp[2] + wp[3];
    }
}

// ---------------- scan both bucket arrays (1 block) ----------------
__launch_bounds__(256)
__global__ void k_scan2(const int* __restrict__ bsizeE, const int* __restrict__ bsizeP,
                        int* __restrict__ tstart, int* __restrict__ tcur,
                        int* __restrict__ pbase, int* __restrict__ pstart) {
    __shared__ int sm[256];
    int t = threadIdx.x;
    // edge-count scan
    int v = (t < NBK) ? bsizeE[t] : 0;
    sm[t] = v;
    __syncthreads();
    for (int off = 1; off < 256; off <<= 1) {
        int u = (t >= off) ? sm[t - off] : 0;
        __syncthreads();
        sm[t] += u;
        __syncthreads();
    }
    if (t < NBK) { tstart[t] = sm[t] - v; tcur[t] = sm[t] - v; }
    if (t == 0) tstart[NBK] = sm[255];
    __syncthreads();
    // padded-slot scan
    int w = (t < NBK) ? bsizeP[t] : 0;
    sm[t] = w;
    __syncthreads();
    for (int off = 1; off < 256; off <<= 1) {
        int u = (t >= off) ? sm[t - off] : 0;
        __syncthreads();
        sm[t] += u;
        __syncthreads();
    }
    if (t < NBK) pbase[t] = sm[t] - w;
    if (t == 0) pstart[NN] = sm[255];
}

// ---------------- per-node padded offsets (per-bucket local scan) ----------
__launch_bounds__(256)
__global__ void k_apply2(const int* __restrict__ deg, const int* __restrict__ pbase,
                         int* __restrict__ pstart) {
    int b = blockIdx.x, t = threadIdx.x;
    int n = b * NPB + t;
    int v = (n < NN) ? ((deg[n] + 4) & ~3) : 0;
    int inc = v;
    #pragma unroll
    for (int off = 1; off < 64; off <<= 1) {
        int u = __shfl_up(inc, off);
        if ((t & 63) >= off) inc += u;
    }
    __shared__ int wsum[4];
    if ((t & 63) == 63) wsum[t >> 6] = inc;
    __syncthreads();
    int w = t >> 6, woff = 0;
    #pragma unroll
    for (int k = 0; k < 4; ++k) if (k < w) woff += wsum[k];
    if (n < NN) pstart[n] = inc - v + woff + pbase[b];
}

// ---------------- partition edges into dst-buckets (coalesced runs) --------
__launch_bounds__(256)
__global__ void k_part(const int* __restrict__ ei, int* __restrict__ tcur,
                       unsigned* __restrict__ tmp) {
    __shared__ int cnt[NBK], base[NBK], lcur[NBK];
    int t = threadIdx.x;
    for (int i = t; i < NBK; i += 256) cnt[i] = 0;
    __syncthreads();
    int e0 = blockIdx.x * EPB;
    #pragma unroll
    for (int j = 0; j < 16; ++j) {
        int e = e0 + j * 256 + t;
        if (e < NE) atomicAdd(&cnt[ei[NE + e] >> 8], 1);
    }
    __syncthreads();
    for (int i = t; i < NBK; i += 256) {
        base[i] = cnt[i] ? atomicAdd(&tcur[i], cnt[i]) : 0;
        lcur[i] = 0;
    }
    __syncthreads();
    #pragma unroll
    for (int j = 0; j < 16; ++j) {
        int e = e0 + j * 256 + t;
        if (e < NE) {
            int d = ei[NE + e], s = ei[e];
            int b = d >> 8;
            int r = atomicAdd(&lcur[b], 1);
            tmp[base[b] + r] = ((unsigned)d << 16) | (unsigned)s;
        }
    }
}

// ---------------- build csr per bucket, LDS-staged, sequential writes ------
__launch_bounds__(256)
__global__ void k_build(const unsigned* __restrict__ tmp, const int* __restrict__ tstart,
                        const int* __restrict__ pstart, ushort* __restrict__ csr) {
    __shared__ ushort buf[8192];
    __shared__ int lcur[NPB];
    int b = blockIdx.x, t = threadIdx.x;
    int n0 = b * NPB, n1 = min(n0 + NPB, NN), nodes = n1 - n0;
    int r0 = pstart[n0], r1 = pstart[n1], S = r1 - r0;   // multiple of 4
    int t0 = tstart[b], t1 = tstart[b + 1];

    if (S <= 8192) {
        for (int i = t; i < (S >> 1); i += 256) ((unsigned*)buf)[i] = 0;
        __syncthreads();
        if (t < nodes) {
            int p = pstart[n0 + t] - r0;
            lcur[t] = p + 1;
            buf[p] = (ushort)(n0 + t);               // self-loop first
        }
        __syncthreads();
        for (int e = t0 + t; e < t1; e += 256) {
            unsigned u = tmp[e];
            int d = (int)(u >> 16) - n0;
            int slot = atomicAdd(&lcur[d], 1);
            buf[slot] = (ushort)(u & 0xffffu);
        }
        __syncthreads();
        unsigned* dst = (unsigned*)(csr + r0);
        for (int i = t; i < (S >> 1); i += 256) dst[i] = ((unsigned*)buf)[i];
    } else {
        for (int i = t; i < S; i += 256) csr[r0 + i] = 0;
        __syncthreads();
        if (t < nodes) {
            int p = pstart[n0 + t];
            lcur[t] = p + 1;
            csr[p] = (ushort)(n0 + t);
        }
        __syncthreads();
        for (int e = t0 + t; e < t1; e += 256) {
            unsigned u = tmp[e];
            int d = (int)(u >> 16) - n0;
            int slot = atomicAdd(&lcur[d], 1);
            csr[slot] = (ushort)(u & 0xffffu);
        }
    }
}

// ---------------- weight transpose+convert: Wt[n][k] bf16 ----------------
__global__ void k_wt(const float* __restrict__ W0, const float* __restrict__ Wc,
                     ushort* __restrict__ Wt) {
    int i = blockIdx.x * 256 + threadIdx.x;   // 0 .. 4*16384-1
    int m = i >> 14;
    int r = i & 16383;
    int k = r >> 7, n = r & 127;
    const float* src = (m == 0) ? W0 : (Wc + (size_t)(m - 1) * DH * DH);
    Wt[(size_t)m * DH * DH + n * DH + k] = f2b(src[r]);
}

// ---------------- MFMA GEMM (+ fused attention dots) ----------------------
// One wave per 16 rows. LDS-staged epilogue: repack C tile per wave (private
// LDS, no barrier) -> 4x ds_read_b128 + 4x coalesced dwordx4 stores.
#define CST 136     // LDS row stride (ushorts): 272 B, 16B-aligned, bank-rotated
template<bool AF32, bool DOTS>
__launch_bounds__(256)
__global__ void k_gemm_mfma(const void* __restrict__ Av, const ushort* __restrict__ Wt,
                            const float* __restrict__ bias, ushort* __restrict__ C,
                            int relu, const float* __restrict__ avs,
                            const float* __restrict__ avd,
                            float* __restrict__ asrc, float* __restrict__ adst) {
    __shared__ ushort sc[4][16 * CST];
    int wid = (blockIdx.x * blockDim.x + threadIdx.x) >> 6;
    int lane = threadIdx.x & 63;
    int row0 = wid * 16;
    if (row0 >= NN) return;
    int mrow = lane & 15;
    int quad = lane >> 4;
    int arow = row0 + mrow;
    ushort* my = sc[(threadIdx.x >> 6)];

    f32x4 acc[8];
    #pragma unroll
    for (int t = 0; t < 8; ++t)
        #pragma unroll
        for (int r = 0; r < 4; ++r) acc[t][r] = 0.f;

    #pragma unroll
    for (int ks = 0; ks < 4; ++ks) {
        int k0 = ks * 32 + quad * 8;
        bfx8 a;
        if (AF32) {
            const float* ap = (const float*)Av + (size_t)arow * DH + k0;
            union { ushort s[8]; bfx8 v; } u;
            #pragma unroll
            for (int j = 0; j < 8; ++j) u.s[j] = f2b(ap[j]);
            a = u.v;
        } else {
            a = *(const bfx8*)((const ushort*)Av + (size_t)arow * DH + k0);
        }
        #pragma unroll
        for (int t = 0; t < 8; ++t) {
            bfx8 b = *(const bfx8*)(Wt + (size_t)(t * 16 + mrow) * DH + k0);
            acc[t] = __builtin_amdgcn_mfma_f32_16x16x32_bf16(a, b, acc[t], 0, 0, 0);
        }
    }

    // epilogue: bias+relu, stage to private LDS tile, then coalesced stores
    #pragma unroll
    for (int t = 0; t < 8; ++t) {
        int col = t * 16 + mrow;
        float bv = bias ? bias[col] : 0.f;
        #pragma unroll
        for (int r = 0; r < 4; ++r) {
            float v = acc[t][r] + bv;
            if (relu) v = fmaxf(v, 0.f);
            my[(quad * 4 + r) * CST + col] = f2b(v);
        }
    }
    #pragma unroll
    for (int i = 0; i < 4; ++i) {
        int idx = i * 64 + lane;          // 0..255 : 16 rows x 16 uint4
        int row = idx >> 4;
        int c16 = idx & 15;
        uint4 u = *(const uint4*)(my + row * CST + c16 * 8);
        *(uint4*)(C + (size_t)(row0 + row) * DH + c16 * 8) = u;
    }

    if (DOTS) {
        float av[8], dv[8];
        #pragma unroll
        for (int t = 0; t < 8; ++t) {
            av[t] = avs[t * 16 + mrow];
            dv[t] = avd[t * 16 + mrow];
        }
        int orow = row0 + quad * 4;
        #pragma unroll
        for (int r = 0; r < 4; ++r) {
            float ps = 0.f, pd = 0.f;
            #pragma unroll
            for (int t = 0; t < 8; ++t) {
                ps += acc[t][r] * av[t];
                pd += acc[t][r] * dv[t];
            }
            #pragma unroll
            for (int off = 1; off < 16; off <<= 1) {
                ps += __shfl_xor(ps, off);
                pd += __shfl_xor(pd, off);
            }
            if (mrow == 0) {
                asrc[orow + r] = ps;
                adst[orow + r] = pd;
            }
        }
    }
}

// ---------------- fused segment softmax + weighted aggregate (bf16 h) -------
// one wave per node; padded segments (x4, zero-pad) -> unguarded 4x-unrolled
// dwordx4 gathers (16 edges in flight), lane = (edge-group g, feat-block fidx).
__launch_bounds__(256)
__global__ void k_aggr(const ushort* __restrict__ h, const float* __restrict__ asrc,
                       const float* __restrict__ adst, const int* __restrict__ pstart,
                       const int* __restrict__ deg, const ushort* __restrict__ csr,
                       const float* __restrict__ bias, ushort* __restrict__ hout) {
    int wid = (blockIdx.x * blockDim.x + threadIdx.x) >> 6;
    int lane = threadIdx.x & 63;
    if (wid >= NN) return;
    int start = pstart[wid];
    int cnt = deg[wid] + 1;
    float ad = adst[wid];

    if (cnt <= 64) {
        int s = csr[start + lane];               // pads are 0 (valid index)
        float e = -1e30f;
        if (lane < cnt) {
            float t = asrc[s] + ad;
            e = fmaxf(t, 0.f) + 0.2f * fminf(t, 0.f);
        }
        float m = e;
        #pragma unroll
        for (int off = 32; off; off >>= 1) m = fmaxf(m, __shfl_xor(m, off));
        float w = (lane < cnt) ? __expf(e - m) : 0.f;
        float dsum = w;
        #pragma unroll
        for (int off = 32; off; off >>= 1) dsum += __shfl_xor(dsum, off);

        int g = lane >> 4, fidx = lane & 15;
        float acc[8];
        #pragma unroll
        for (int k = 0; k < 8; ++k) acc[k] = 0.f;

        int steps = (cnt + 3) >> 2;
        const uint4* hp = (const uint4*)h;
        int j = 0;
        for (; j + 3 < steps; j += 4) {
            int   e0 = j * 4 + g,      e1 = e0 + 4,  e2 = e0 + 8,  e3 = e0 + 12;
            float w0 = __shfl(w, e0),  w1 = __shfl(w, e1);
            float w2 = __shfl(w, e2),  w3 = __shfl(w, e3);
            int   s0 = __shfl(s, e0),  s1 = __shfl(s, e1);
            int   s2 = __shfl(s, e2),  s3 = __shfl(s, e3);
            uint4 u0 = hp[(size_t)s0 * 16 + fidx];
            uint4 u1 = hp[(size_t)s1 * 16 + fidx];
            uint4 u2 = hp[(size_t)s2 * 16 + fidx];
            uint4 u3 = hp[(size_t)s3 * 16 + fidx];
            acc[0] += w0 * lo16(u0.x); acc[1] += w0 * hi16(u0.x);
            acc[2] += w0 * lo16(u0.y); acc[3] += w0 * hi16(u0.y);
            acc[4] += w0 * lo16(u0.z); acc[5] += w0 * hi16(u0.z);
            acc[6] += w0 * lo16(u0.w); acc[7] += w0 * hi16(u0.w);
            acc[0] += w1 * lo16(u1.x); acc[1] += w1 * hi16(u1.x);
            acc[2] += w1 * lo16(u1.y); acc[3] += w1 * hi16(u1.y);
            acc[4] += w1 * lo16(u1.z); acc[5] += w1 * hi16(u1.z);
            acc[6] += w1 * lo16(u1.w); acc[7] += w1 * hi16(u1.w);
            acc[0] += w2 * lo16(u2.x); acc[1] += w2 * hi16(u2.x);
            acc[2] += w2 * lo16(u2.y); acc[3] += w2 * hi16(u2.y);
            acc[4] += w2 * lo16(u2.z); acc[5] += w2 * hi16(u2.z);
            acc[6] += w2 * lo16(u2.w); acc[7] += w2 * hi16(u2.w);
            acc[0] += w3 * lo16(u3.x); acc[1] += w3 * hi16(u3.x);
            acc[2] += w3 * lo16(u3.y); acc[3] += w3 * hi16(u3.y);
            acc[4] += w3 * lo16(u3.z); acc[5] += w3 * hi16(u3.z);
            acc[6] += w3 * lo16(u3.w); acc[7] += w3 * hi16(u3.w);
        }
        for (; j < steps; ++j) {
            int e0 = j * 4 + g;
            float w0 = __shfl(w, e0);
            int   s0 = __shfl(s, e0);
            uint4 u0 = hp[(size_t)s0 * 16 + fidx];
            acc[0] += w0 * lo16(u0.x); acc[1] += w0 * hi16(u0.x);
            acc[2] += w0 * lo16(u0.y); acc[3] += w0 * hi16(u0.y);
            acc[4] += w0 * lo16(u0.z); acc[5] += w0 * hi16(u0.z);
            acc[6] += w0 * lo16(u0.w); acc[7] += w0 * hi16(u0.w);
        }
        #pragma unroll
        for (int k = 0; k < 8; ++k) {
            acc[k] += __shfl_xor(acc[k], 16);
            acc[k] += __shfl_xor(acc[k], 32);
        }
        if (g == 0) {
            float inv = 1.f / (dsum + 1e-16f);
            const float4* bp = (const float4*)bias;
            float4 b0 = bp[fidx * 2], b1 = bp[fidx * 2 + 1];
            uint4 o;
            o.x = pk2(fmaxf(acc[0] * inv + b0.x, 0.f), fmaxf(acc[1] * inv + b0.y, 0.f));
            o.y = pk2(fmaxf(acc[2] * inv + b0.z, 0.f), fmaxf(acc[3] * inv + b0.w, 0.f));
            o.z = pk2(fmaxf(acc[4] * inv + b1.x, 0.f), fmaxf(acc[5] * inv + b1.y, 0.f));
            o.w = pk2(fmaxf(acc[6] * inv + b1.z, 0.f), fmaxf(acc[7] * inv + b1.w, 0.f));
            ((uint4*)hout)[(size_t)wid * 16 + fidx] = o;
        }
        return;
    }

    // generic fallback (deg > 64) — never with this data
    float m = -1e30f;
    for (int i0 = start; i0 < start + cnt; i0 += 64) {
        int i = i0 + lane;
        float e = -1e30f;
        if (i < start + cnt) {
            int s = csr[i];
            float t = asrc[s] + ad;
            e = fmaxf(t, 0.f) + 0.2f * fminf(t, 0.f);
        }
        m = fmaxf(m, e);
    }
    #pragma unroll
    for (int off = 32; off; off >>= 1) m = fmaxf(m, __shfl_xor(m, off));

    float accx = 0.f, accy = 0.f, dsum = 0.f;
    for (int i0 = start; i0 < start + cnt; i0 += 64) {
        int i = i0 + lane;
        int s = 0; float w = 0.f;
        if (i < start + cnt) {
            s = csr[i];
            float t = asrc[s] + ad;
            float e = fmaxf(t, 0.f) + 0.2f * fminf(t, 0.f);
            w = __expf(e - m);
        }
        dsum += w;
        int cl = min(64, start + cnt - i0);
        for (int j = 0; j < cl; ++j) {
            int   sj = __shfl(s, j);
            float wj = __shfl(w, j);
            unsigned u = *(const unsigned*)(h + (size_t)sj * DH + lane * 2);
            accx += wj * lo16(u);
            accy += wj * hi16(u);
        }
    }
    #pragma unroll
    for (int off = 32; off; off >>= 1) dsum += __shfl_xor(dsum, off);

    float inv = 1.f / (dsum + 1e-16f);
    float ox = fmaxf(accx * inv + bias[lane * 2], 0.f);
    float oy = fmaxf(accy * inv + bias[lane * 2 + 1], 0.f);
    *(unsigned*)(hout + (size_t)wid * DH + lane * 2) = pk2(ox, oy);
}

// ---------------- mean pool (batch sorted, bf16 h) ----------------
__launch_bounds__(128)
__global__ void k_pool(const ushort* __restrict__ h, const int* __restrict__ batch,
                       float* __restrict__ gsum, int* __restrict__ gcnt) {
    int f = threadIdx.x;
    int n0 = blockIdx.x * 64;
    int n1 = min(n0 + 64, NN);
    float acc = 0.f; int run = 0;
    int gcur = batch[n0];
    for (int nd = n0; nd < n1; ++nd) {
        int g = batch[nd];
        if (g != gcur) {
            atomicAdd(&gsum[gcur * DH + f], acc);
            if (f == 0) atomicAdd(&gcnt[gcur], run);
            acc = 0.f; run = 0; gcur = g;
        }
        acc += b2f(h[(size_t)nd * DH + f]);
        run += 1;
    }
    atomicAdd(&gsum[gcur * DH + f], acc);
    if (f == 0) atomicAdd(&gcnt[gcur], run);
}

// ---------------- final linear [64,128]@[128,10] -> fp32 out ----------------
__global__ void k_final(const float* __restrict__ gsum, const int* __restrict__ gcnt,
                        const float* __restrict__ W1, const float* __restrict__ b1,
                        float* __restrict__ out) {
    int t = threadIdx.x;
    if (t >= NG * 10) return;
    int g = t / 10, o = t % 10;
    float inv = 1.f / fmaxf((float)gcnt[g], 1.f);
    float acc = 0.f;
    for (int f = 0; f < DH; ++f) acc += gsum[g * DH + f] * W1[f * 10 + o];
    out[t] = acc * inv + b1[o];
}

extern "C" void kernel_launch(void* const* d_in, const int* in_sizes, int n_in,
                              void* d_out, int out_size, void* d_ws, size_t ws_size,
                              hipStream_t stream) {
    const float* x       = (const float*)d_in[0];
    const int*   ei      = (const int*)d_in[1];
    const int*   batch   = (const int*)d_in[3];
    const float* W0      = (const float*)d_in[4];
    const float* b0      = (const float*)d_in[5];
    const float* Wc      = (const float*)d_in[6];
    const float* att_src = (const float*)d_in[7];
    const float* att_dst = (const float*)d_in[8];
    const float* bc      = (const float*)d_in[9];
    const float* W1      = (const float*)d_in[10];
    const float* b1      = (const float*)d_in[11];
    float* out = (float*)d_out;

    char* ws = (char*)d_ws;
    size_t off = 0;
    auto alloc = [&](size_t bytes) {
        void* p = ws + off;
        off += (bytes + 255) & ~(size_t)255;
        return p;
    };
    ushort*   hA     = (ushort*)alloc((size_t)NN * DH * 2);
    ushort*   hB     = (ushort*)alloc((size_t)NN * DH * 2);
    ushort*   Wt     = (ushort*)alloc((size_t)4 * DH * DH * 2);
    int*      pstart = (int*)alloc((NN + 1) * 4);
    ushort*   csr    = (ushort*)alloc((size_t)(NE + 4 * NN + 64) * 2);
    unsigned* tmp    = (unsigned*)alloc((size_t)NE * 4);
    float*    asrc   = (float*)alloc(NN * 4);
    float*    adst   = (float*)alloc(NN * 4);
    int*      deg    = (int*)alloc(NN * 4);
    int*      bsizeE = (int*)alloc((NBK + 1) * 4);
    int*      bsizeP = (int*)alloc((NBK + 1) * 4);
    int*      tstart = (int*)alloc((NBK + 1) * 4);
    int*      tcur   = (int*)alloc((NBK + 1) * 4);
    int*      pbase  = (int*)alloc((NBK + 1) * 4);
    float*    gsum   = (float*)alloc(NG * DH * 4);   // gsum+gcnt adjacent
    int*      gcnt   = (int*)alloc(NG * 4);

    hipMemsetAsync(deg, 0, NN * 4, stream);
    hipMemsetAsync(gsum, 0, NG * DH * 4 + 256, stream);  // covers gcnt too

    k_hist<<<(NE + 255) / 256, 256, 0, stream>>>(ei, deg);
    k_sizes<<<NBK, 256, 0, stream>>>(deg, bsizeE, bsizeP);
    k_scan2<<<1, 256, 0, stream>>>(bsizeE, bsizeP, tstart, tcur, pbase, pstart);
    k_apply2<<<NBK, 256, 0, stream>>>(deg, pbase, pstart);
    k_part<<<NPBLK, 256, 0, stream>>>(ei, tcur, tmp);
    k_build<<<NBK, 256, 0, stream>>>(tmp, tstart, pstart, csr);
    k_wt<<<4 * DH * DH / 256, 256, 0, stream>>>(W0, Wc, Wt);

    const int NWAVE = NN / 16;                       // 3125
    const int GEMMB = (NWAVE + 3) / 4;               // 782 blocks of 4 waves

    k_gemm_mfma<true, false><<<GEMMB, 256, 0, stream>>>(
        x, Wt, b0, hB, 1, nullptr, nullptr, nullptr, nullptr);

    for (int l = 0; l < 3; ++l) {
        k_gemm_mfma<false, true><<<GEMMB, 256, 0, stream>>>(
            hB, Wt + (size_t)(l + 1) * DH * DH, nullptr, hA, 0,
            att_src + l * DH, att_dst + l * DH, asrc, adst);
        k_aggr<<<(NN + 3) / 4, 256, 0, stream>>>(hA, asrc, adst, pstart, deg, csr,
                                                 bc + l * DH, hB);
    }

    k_pool<<<(NN + 63) / 64, 128, 0, stream>>>(hB, batch, gsum, gcnt);
    k_final<<<1, NG * 10, 0, stream>>>(gsum, gcnt, W1, b1, out);
}

// Round 9
// 349.493 us; speedup vs baseline: 2.1205x; 1.1329x over previous
//
#include <hip/hip_runtime.h>
#include <hip/hip_bf16.h>

#define NN 50000
#define NE 800000
#define NG 64
#define DH 128

#define NPB 256                          // nodes per bucket
#define NBK ((NN + NPB - 1) / NPB)       // 196 buckets
#define EPB 4096                         // edges per partition block
#define NPBLK ((NE + EPB - 1) / EPB)     // 196
#define CAPB 5120                        // tmp slots per bucket (4081 avg + 16 sigma)
#define GEMMB 782                        // (50000/16+3)/4 blocks of 4 waves
#define CST 136                          // epilogue LDS row stride (ushorts)
#define SMEM_BYTES 17408                 // max(4*16*CST*2, 8192*2+NPB*4) — equal!

typedef __bf16 bfx8 __attribute__((ext_vector_type(8)));
typedef float  f32x4 __attribute__((ext_vector_type(4)));

__device__ __forceinline__ ushort f2b(float f) {        // fp32 -> bf16 RNE
    unsigned b = __float_as_uint(f);
    b += 0x7fff + ((b >> 16) & 1);
    return (ushort)(b >> 16);
}
__device__ __forceinline__ float b2f(ushort s) {
    return __uint_as_float((unsigned)s << 16);
}
__device__ __forceinline__ float lo16(unsigned u) { return __uint_as_float(u << 16); }
__device__ __forceinline__ float hi16(unsigned u) { return __uint_as_float(u & 0xffff0000u); }
__device__ __forceinline__ unsigned pk2(float a, float b) {
    return (unsigned)f2b(a) | ((unsigned)f2b(b) << 16);
}

// ---------------- partition edges into dst-buckets (+ fused weight prep) ----
// blocks [0,NPBLK): bin 4096 edges each into fixed-capacity bucket regions.
// blocks [NPBLK,NPBLK+256): transpose/convert weights to Wt[n][k] bf16.
__launch_bounds__(256)
__global__ void k_partwt(const int* __restrict__ ei, int* __restrict__ gcur,
                         unsigned* __restrict__ tmp,
                         const float* __restrict__ W0, const float* __restrict__ Wc,
                         ushort* __restrict__ Wt) {
    int t = threadIdx.x;
    if (blockIdx.x >= NPBLK) {
        int i = (blockIdx.x - NPBLK) * 256 + t;      // 0 .. 65535
        int m = i >> 14;
        int r = i & 16383;
        int k = r >> 7, n = r & 127;
        const float* src = (m == 0) ? W0 : (Wc + (size_t)(m - 1) * DH * DH);
        Wt[(size_t)m * DH * DH + n * DH + k] = f2b(src[r]);
        return;
    }
    __shared__ int cnt[NBK], base[NBK], lcur[NBK];
    for (int i = t; i < NBK; i += 256) cnt[i] = 0;
    __syncthreads();
    int e0 = blockIdx.x * EPB;
    int dreg[16];
    #pragma unroll
    for (int j = 0; j < 16; ++j) {
        int e = e0 + j * 256 + t;
        dreg[j] = (e < NE) ? ei[NE + e] : -1;
        if (e < NE) atomicAdd(&cnt[dreg[j] >> 8], 1);
    }
    __syncthreads();
    for (int i = t; i < NBK; i += 256) {
        base[i] = cnt[i] ? atomicAdd(&gcur[i], cnt[i]) : 0;
        lcur[i] = 0;
    }
    __syncthreads();
    #pragma unroll
    for (int j = 0; j < 16; ++j) {
        int e = e0 + j * 256 + t;
        if (e < NE) {
            int d = dreg[j], s = ei[e];
            int b = d >> 8;
            int r = atomicAdd(&lcur[b], 1);
            tmp[(size_t)b * CAPB + base[b] + r] = ((unsigned)(d & 255) << 16) | (unsigned)s;
        }
    }
}

// ---------------- per-bucket degree count + local padded offsets ----------
__launch_bounds__(256)
__global__ void k_bcount(const unsigned* __restrict__ tmp, const int* __restrict__ gcur,
                         int* __restrict__ deg, int* __restrict__ ploc,
                         int* __restrict__ bsizeP) {
    __shared__ int dcnt[NPB];
    int b = blockIdx.x, t = threadIdx.x;
    dcnt[t] = 0;
    __syncthreads();
    int ne = gcur[b];
    for (int e = t; e < ne; e += 256)
        atomicAdd(&dcnt[tmp[(size_t)b * CAPB + e] >> 16], 1);
    __syncthreads();
    int n = b * NPB + t;
    int d = (n < NN) ? dcnt[t] : 0;
    int p = (n < NN) ? ((d + 4) & ~3) : 0;           // align4(deg+1)
    int inc = p;
    #pragma unroll
    for (int off = 1; off < 64; off <<= 1) {
        int u = __shfl_up(inc, off);
        if ((t & 63) >= off) inc += u;
    }
    __shared__ int wsum[4];
    if ((t & 63) == 63) wsum[t >> 6] = inc;
    __syncthreads();
    int w = t >> 6, woff = 0;
    #pragma unroll
    for (int k = 0; k < 4; ++k) if (k < w) woff += wsum[k];
    int lofs = inc - p + woff;
    if (n < NN) { deg[n] = d; ploc[n] = lofs; }
    if (t == 255) bsizeP[b] = lofs + p;              // bucket padded total
}

// ---------------- scan bucket padded sums (1 block) ----------------
__launch_bounds__(256)
__global__ void k_bscan(const int* __restrict__ bsizeP, int* __restrict__ pbase) {
    __shared__ int sm[256];
    int t = threadIdx.x;
    int v = (t < NBK) ? bsizeP[t] : 0;
    sm[t] = v;
    __syncthreads();
    for (int off = 1; off < 256; off <<= 1) {
        int u = (t >= off) ? sm[t - off] : 0;
        __syncthreads();
        sm[t] += u;
        __syncthreads();
    }
    if (t < NBK) pbase[t] = sm[t] - v;
    if (t == 255) pbase[NBK] = sm[255];
}

// ---------------- MFMA GEMM body (shared by fused kernels) ----------------
// One wave per 16 rows. A/B frags from global; D: col=lane&15, row=quad*4+reg.
// Epilogue staged per-wave in LDS -> coalesced dwordx4 stores.
template<bool AF32, bool DOTS>
__device__ __forceinline__ void gemm_body(char* smem, int gblk,
        const void* __restrict__ Av, const ushort* __restrict__ Wt,
        const float* __restrict__ bias, ushort* __restrict__ C, int relu,
        const float* __restrict__ avs, const float* __restrict__ avd,
        float* __restrict__ asrc, float* __restrict__ adst) {
    int tid = threadIdx.x;
    int wid = (gblk * 256 + tid) >> 6;
    int lane = tid & 63;
    int row0 = wid * 16;
    if (row0 >= NN) return;
    int mrow = lane & 15;
    int quad = lane >> 4;
    int arow = row0 + mrow;
    ushort* my = (ushort*)smem + (tid >> 6) * 16 * CST;

    f32x4 acc[8];
    #pragma unroll
    for (int t = 0; t < 8; ++t)
        #pragma unroll
        for (int r = 0; r < 4; ++r) acc[t][r] = 0.f;

    #pragma unroll
    for (int ks = 0; ks < 4; ++ks) {
        int k0 = ks * 32 + quad * 8;
        bfx8 a;
        if (AF32) {
            const float* ap = (const float*)Av + (size_t)arow * DH + k0;
            union { ushort s[8]; bfx8 v; } u;
            #pragma unroll
            for (int j = 0; j < 8; ++j) u.s[j] = f2b(ap[j]);
            a = u.v;
        } else {
            a = *(const bfx8*)((const ushort*)Av + (size_t)arow * DH + k0);
        }
        #pragma unroll
        for (int t = 0; t < 8; ++t) {
            bfx8 b = *(const bfx8*)(Wt + (size_t)(t * 16 + mrow) * DH + k0);
            acc[t] = __builtin_amdgcn_mfma_f32_16x16x32_bf16(a, b, acc[t], 0, 0, 0);
        }
    }

    #pragma unroll
    for (int t = 0; t < 8; ++t) {
        int col = t * 16 + mrow;
        float bv = bias ? bias[col] : 0.f;
        #pragma unroll
        for (int r = 0; r < 4; ++r) {
            float v = acc[t][r] + bv;
            if (relu) v = fmaxf(v, 0.f);
            my[(quad * 4 + r) * CST + col] = f2b(v);
        }
    }
    #pragma unroll
    for (int i = 0; i < 4; ++i) {
        int idx = i * 64 + lane;
        int row = idx >> 4;
        int c16 = idx & 15;
        uint4 u = *(const uint4*)(my + row * CST + c16 * 8);
        *(uint4*)(C + (size_t)(row0 + row) * DH + c16 * 8) = u;
    }

    if (DOTS) {
        float av[8], dv[8];
        #pragma unroll
        for (int t = 0; t < 8; ++t) {
            av[t] = avs[t * 16 + mrow];
            dv[t] = avd[t * 16 + mrow];
        }
        int orow = row0 + quad * 4;
        #pragma unroll
        for (int r = 0; r < 4; ++r) {
            float ps = 0.f, pd = 0.f;
            #pragma unroll
            for (int t = 0; t < 8; ++t) {
                ps += acc[t][r] * av[t];
                pd += acc[t][r] * dv[t];
            }
            #pragma unroll
            for (int off = 1; off < 16; off <<= 1) {
                ps += __shfl_xor(ps, off);
                pd += __shfl_xor(pd, off);
            }
            if (mrow == 0) {
                asrc[orow + r] = ps;
                adst[orow + r] = pd;
            }
        }
    }
}

// ---------------- fused: GEMM-1 (fp32 x -> bf16 hB) + CSR assembly --------
// blocks [0,GEMMB): GEMM.  blocks [GEMMB,GEMMB+NBK): build csr per bucket.
__launch_bounds__(256)
__global__ void k_buildgemm(const unsigned* __restrict__ tmp, const int* __restrict__ gcur,
                            const int* __restrict__ pbase, const int* __restrict__ ploc,
                            int* __restrict__ pstart, ushort* __restrict__ csr,
                            const float* __restrict__ x, const ushort* __restrict__ Wt,
                            const float* __restrict__ b0, ushort* __restrict__ hB) {
    __shared__ char smem[SMEM_BYTES];
    int t = threadIdx.x;
    if (blockIdx.x < GEMMB) {
        gemm_body<true, false>(smem, blockIdx.x, x, Wt, b0, hB, 1,
                               nullptr, nullptr, nullptr, nullptr);
        return;
    }
    int b = blockIdx.x - GEMMB;
    ushort* buf = (ushort*)smem;                      // 8192 ushorts
    int* lcur = (int*)(smem + 16384);                 // NPB ints
    int n0 = b * NPB, n1 = min(n0 + NPB, NN), nodes = n1 - n0;
    int r0 = pbase[b], S = pbase[b + 1] - r0;         // multiple of 4
    int ne = gcur[b];

    if (S <= 8192) {
        for (int i = t; i < (S >> 1); i += 256) ((unsigned*)buf)[i] = 0;
        __syncthreads();
        if (t < nodes) {
            int lp = ploc[n0 + t];
            pstart[n0 + t] = r0 + lp;
            lcur[t] = lp + 1;
            buf[lp] = (ushort)(n0 + t);               // self-loop first
        }
        __syncthreads();
        for (int e = t; e < ne; e += 256) {
            unsigned u = tmp[(size_t)b * CAPB + e];
            int slot = atomicAdd(&lcur[u >> 16], 1);
            buf[slot] = (ushort)(u & 0xffffu);
        }
        __syncthreads();
        unsigned* dst = (unsigned*)(csr + r0);
        for (int i = t; i < (S >> 1); i += 256) dst[i] = ((unsigned*)buf)[i];
    } else {
        // fallback (never with this data): direct global writes
        for (int i = t; i < S; i += 256) csr[r0 + i] = 0;
        __syncthreads();
        if (t < nodes) {
            int lp = ploc[n0 + t];
            pstart[n0 + t] = r0 + lp;
            lcur[t] = r0 + lp + 1;
            csr[r0 + lp] = (ushort)(n0 + t);
        }
        __syncthreads();
        for (int e = t; e < ne; e += 256) {
            unsigned u = tmp[(size_t)b * CAPB + e];
            int slot = atomicAdd(&lcur[u >> 16], 1);
            csr[slot] = (ushort)(u & 0xffffu);
        }
    }
}

// ---------------- GEMM + fused attention dots (layers) ----------------
__launch_bounds__(256)
__global__ void k_gemmdots(const ushort* __restrict__ hB, const ushort* __restrict__ Wt,
                           ushort* __restrict__ hA,
                           const float* __restrict__ avs, const float* __restrict__ avd,
                           float* __restrict__ asrc, float* __restrict__ adst) {
    __shared__ char smem[SMEM_BYTES];
    gemm_body<false, true>(smem, blockIdx.x, hB, Wt, nullptr, hA, 0,
                           avs, avd, asrc, adst);
}

// ---------------- fused segment softmax + weighted aggregate (bf16 h) -------
__launch_bounds__(256)
__global__ void k_aggr(const ushort* __restrict__ h, const float* __restrict__ asrc,
                       const float* __restrict__ adst, const int* __restrict__ pstart,
                       const int* __restrict__ deg, const ushort* __restrict__ csr,
                       const float* __restrict__ bias, ushort* __restrict__ hout) {
    int wid = (blockIdx.x * blockDim.x + threadIdx.x) >> 6;
    int lane = threadIdx.x & 63;
    if (wid >= NN) return;
    int start = pstart[wid];
    int cnt = deg[wid] + 1;
    float ad = adst[wid];

    if (cnt <= 64) {
        int s = csr[start + lane];               // pads are 0 (valid index)
        float e = -1e30f;
        if (lane < cnt) {
            float t = asrc[s] + ad;
            e = fmaxf(t, 0.f) + 0.2f * fminf(t, 0.f);
        }
        float m = e;
        #pragma unroll
        for (int off = 32; off; off >>= 1) m = fmaxf(m, __shfl_xor(m, off));
        float w = (lane < cnt) ? __expf(e - m) : 0.f;
        float dsum = w;
        #pragma unroll
        for (int off = 32; off; off >>= 1) dsum += __shfl_xor(dsum, off);

        int g = lane >> 4, fidx = lane & 15;
        float acc[8];
        #pragma unroll
        for (int k = 0; k < 8; ++k) acc[k] = 0.f;

        int steps = (cnt + 3) >> 2;
        const uint4* hp = (const uint4*)h;
        int j = 0;
        for (; j + 3 < steps; j += 4) {
            int   e0 = j * 4 + g,      e1 = e0 + 4,  e2 = e0 + 8,  e3 = e0 + 12;
            float w0 = __shfl(w, e0),  w1 = __shfl(w, e1);
            float w2 = __shfl(w, e2),  w3 = __shfl(w, e3);
            int   s0 = __shfl(s, e0),  s1 = __shfl(s, e1);
            int   s2 = __shfl(s, e2),  s3 = __shfl(s, e3);
            uint4 u0 = hp[(size_t)s0 * 16 + fidx];
            uint4 u1 = hp[(size_t)s1 * 16 + fidx];
            uint4 u2 = hp[(size_t)s2 * 16 + fidx];
            uint4 u3 = hp[(size_t)s3 * 16 + fidx];
            acc[0] += w0 * lo16(u0.x); acc[1] += w0 * hi16(u0.x);
            acc[2] += w0 * lo16(u0.y); acc[3] += w0 * hi16(u0.y);
            acc[4] += w0 * lo16(u0.z); acc[5] += w0 * hi16(u0.z);
            acc[6] += w0 * lo16(u0.w); acc[7] += w0 * hi16(u0.w);
            acc[0] += w1 * lo16(u1.x); acc[1] += w1 * hi16(u1.x);
            acc[2] += w1 * lo16(u1.y); acc[3] += w1 * hi16(u1.y);
            acc[4] += w1 * lo16(u1.z); acc[5] += w1 * hi16(u1.z);
            acc[6] += w1 * lo16(u1.w); acc[7] += w1 * hi16(u1.w);
            acc[0] += w2 * lo16(u2.x); acc[1] += w2 * hi16(u2.x);
            acc[2] += w2 * lo16(u2.y); acc[3] += w2 * hi16(u2.y);
            acc[4] += w2 * lo16(u2.z); acc[5] += w2 * hi16(u2.z);
            acc[6] += w2 * lo16(u2.w); acc[7] += w2 * hi16(u2.w);
            acc[0] += w3 * lo16(u3.x); acc[1] += w3 * hi16(u3.x);
            acc[2] += w3 * lo16(u3.y); acc[3] += w3 * hi16(u3.y);
            acc[4] += w3 * lo16(u3.z); acc[5] += w3 * hi16(u3.z);
            acc[6] += w3 * lo16(u3.w); acc[7] += w3 * hi16(u3.w);
        }
        for (; j < steps; ++j) {
            int e0 = j * 4 + g;
            float w0 = __shfl(w, e0);
            int   s0 = __shfl(s, e0);
            uint4 u0 = hp[(size_t)s0 * 16 + fidx];
            acc[0] += w0 * lo16(u0.x); acc[1] += w0 * hi16(u0.x);
            acc[2] += w0 * lo16(u0.y); acc[3] += w0 * hi16(u0.y);
            acc[4] += w0 * lo16(u0.z); acc[5] += w0 * hi16(u0.z);
            acc[6] += w0 * lo16(u0.w); acc[7] += w0 * hi16(u0.w);
        }
        #pragma unroll
        for (int k = 0; k < 8; ++k) {
            acc[k] += __shfl_xor(acc[k], 16);
            acc[k] += __shfl_xor(acc[k], 32);
        }
        if (g == 0) {
            float inv = 1.f / (dsum + 1e-16f);
            const float4* bp = (const float4*)bias;
            float4 b0 = bp[fidx * 2], b1 = bp[fidx * 2 + 1];
            uint4 o;
            o.x = pk2(fmaxf(acc[0] * inv + b0.x, 0.f), fmaxf(acc[1] * inv + b0.y, 0.f));
            o.y = pk2(fmaxf(acc[2] * inv + b0.z, 0.f), fmaxf(acc[3] * inv + b0.w, 0.f));
            o.z = pk2(fmaxf(acc[4] * inv + b1.x, 0.f), fmaxf(acc[5] * inv + b1.y, 0.f));
            o.w = pk2(fmaxf(acc[6] * inv + b1.z, 0.f), fmaxf(acc[7] * inv + b1.w, 0.f));
            ((uint4*)hout)[(size_t)wid * 16 + fidx] = o;
        }
        return;
    }

    // generic fallback (deg > 64) — never with this data
    float m = -1e30f;
    for (int i0 = start; i0 < start + cnt; i0 += 64) {
        int i = i0 + lane;
        float e = -1e30f;
        if (i < start + cnt) {
            int s = csr[i];
            float t = asrc[s] + ad;
            e = fmaxf(t, 0.f) + 0.2f * fminf(t, 0.f);
        }
        m = fmaxf(m, e);
    }
    #pragma unroll
    for (int off = 32; off; off >>= 1) m = fmaxf(m, __shfl_xor(m, off));

    float accx = 0.f, accy = 0.f, dsum = 0.f;
    for (int i0 = start; i0 < start + cnt; i0 += 64) {
        int i = i0 + lane;
        int s = 0; float w = 0.f;
        if (i < start + cnt) {
            s = csr[i];
            float t = asrc[s] + ad;
            float e = fmaxf(t, 0.f) + 0.2f * fminf(t, 0.f);
            w = __expf(e - m);
        }
        dsum += w;
        int cl = min(64, start + cnt - i0);
        for (int j = 0; j < cl; ++j) {
            int   sj = __shfl(s, j);
            float wj = __shfl(w, j);
            unsigned u = *(const unsigned*)(h + (size_t)sj * DH + lane * 2);
            accx += wj * lo16(u);
            accy += wj * hi16(u);
        }
    }
    #pragma unroll
    for (int off = 32; off; off >>= 1) dsum += __shfl_xor(dsum, off);

    float inv = 1.f / (dsum + 1e-16f);
    float ox = fmaxf(accx * inv + bias[lane * 2], 0.f);
    float oy = fmaxf(accy * inv + bias[lane * 2 + 1], 0.f);
    *(unsigned*)(hout + (size_t)wid * DH + lane * 2) = pk2(ox, oy);
}

// ---------------- mean pool (batch sorted, bf16 h, 2 rows in flight) -------
__launch_bounds__(256)
__global__ void k_pool(const ushort* __restrict__ h, const int* __restrict__ batch,
                       float* __restrict__ gsum, int* __restrict__ gcnt) {
    int slot = threadIdx.x >> 7;          // 0 or 1
    int f = threadIdx.x & 127;
    int n0 = blockIdx.x * 64;
    int n1 = min(n0 + 64, NN);
    int first = n0 + slot;
    if (first >= n1) return;
    float acc = 0.f; int run = 0;
    int gcur = batch[first];
    for (int nd = first; nd < n1; nd += 2) {
        int g = batch[nd];
        if (g != gcur) {
            atomicAdd(&gsum[gcur * DH + f], acc);
            if (f == 0) atomicAdd(&gcnt[gcur], run);
            acc = 0.f; run = 0; gcur = g;
        }
        acc += b2f(h[(size_t)nd * DH + f]);
        run += 1;
    }
    atomicAdd(&gsum[gcur * DH + f], acc);
    if (f == 0) atomicAdd(&gcnt[gcur], run);
}

// ---------------- final linear [64,128]@[128,10] -> fp32 out ----------------
__global__ void k_final(const float* __restrict__ gsum, const int* __restrict__ gcnt,
                        const float* __restrict__ W1, const float* __restrict__ b1,
                        float* __restrict__ out) {
    int t = threadIdx.x;
    if (t >= NG * 10) return;
    int g = t / 10, o = t % 10;
    float inv = 1.f / fmaxf((float)gcnt[g], 1.f);
    float acc = 0.f;
    for (int f = 0; f < DH; ++f) acc += gsum[g * DH + f] * W1[f * 10 + o];
    out[t] = acc * inv + b1[o];
}

extern "C" void kernel_launch(void* const* d_in, const int* in_sizes, int n_in,
                              void* d_out, int out_size, void* d_ws, size_t ws_size,
                              hipStream_t stream) {
    const float* x       = (const float*)d_in[0];
    const int*   ei      = (const int*)d_in[1];
    const int*   batch   = (const int*)d_in[3];
    const float* W0      = (const float*)d_in[4];
    const float* b0      = (const float*)d_in[5];
    const float* Wc      = (const float*)d_in[6];
    const float* att_src = (const float*)d_in[7];
    const float* att_dst = (const float*)d_in[8];
    const float* bc      = (const float*)d_in[9];
    const float* W1      = (const float*)d_in[10];
    const float* b1      = (const float*)d_in[11];
    float* out = (float*)d_out;

    char* ws = (char*)d_ws;
    size_t off = 0;
    auto alloc = [&](size_t bytes) {
        void* p = ws + off;
        off += (bytes + 255) & ~(size_t)255;
        return p;
    };
    ushort*   hA     = (ushort*)alloc((size_t)NN * DH * 2);
    ushort*   hB     = (ushort*)alloc((size_t)NN * DH * 2);
    ushort*   Wt     = (ushort*)alloc((size_t)4 * DH * DH * 2);
    int*      pstart = (int*)alloc((size_t)NN * 4);
    ushort*   csr    = (ushort*)alloc((size_t)(NE + 4 * NN + 64) * 2);
    unsigned* tmp    = (unsigned*)alloc((size_t)NBK * CAPB * 4);
    float*    asrc   = (float*)alloc(NN * 4);
    float*    adst   = (float*)alloc(NN * 4);
    int*      deg    = (int*)alloc(NN * 4);
    int*      ploc   = (int*)alloc(NN * 4);
    int*      gcur   = (int*)alloc((NBK + 1) * 4);
    int*      bsizeP = (int*)alloc((NBK + 1) * 4);
    int*      pbase  = (int*)alloc((NBK + 1) * 4);
    float*    gsum   = (float*)alloc(NG * DH * 4);   // gsum+gcnt adjacent
    int*      gcnt   = (int*)alloc(NG * 4);

    hipMemsetAsync(gcur, 0, (NBK + 1) * 4, stream);
    hipMemsetAsync(gsum, 0, NG * DH * 4 + 256, stream);  // covers gcnt too

    k_partwt<<<NPBLK + 256, 256, 0, stream>>>(ei, gcur, tmp, W0, Wc, Wt);
    k_bcount<<<NBK, 256, 0, stream>>>(tmp, gcur, deg, ploc, bsizeP);
    k_bscan<<<1, 256, 0, stream>>>(bsizeP, pbase);
    k_buildgemm<<<GEMMB + NBK, 256, 0, stream>>>(tmp, gcur, pbase, ploc, pstart, csr,
                                                 x, Wt, b0, hB);

    for (int l = 0; l < 3; ++l) {
        k_gemmdots<<<GEMMB, 256, 0, stream>>>(hB, Wt + (size_t)(l + 1) * DH * DH, hA,
                                              att_src + l * DH, att_dst + l * DH,
                                              asrc, adst);
        k_aggr<<<(NN + 3) / 4, 256, 0, stream>>>(hA, asrc, adst, pstart, deg, csr,
                                                 bc + l * DH, hB);
    }

    k_pool<<<(NN + 63) / 64, 256, 0, stream>>>(hB, batch, gsum, gcnt);
    k_final<<<1, NG * 10, 0, stream>>>(gsum, gcnt, W1, b1, out);
}

// Round 10
// 348.159 us; speedup vs baseline: 2.1286x; 1.0038x over previous
//
#include <hip/hip_runtime.h>
#include <hip/hip_bf16.h>
#include <hip/hip_fp16.h>

#define NN 50000
#define NE 800000
#define NG 64
#define DH 128

#define NPB 256                          // nodes per bucket
#define NBK ((NN + NPB - 1) / NPB)       // 196 buckets
#define EPB 4096                         // edges per partition block
#define NPBLK ((NE + EPB - 1) / EPB)     // 196
#define CAPB 5120                        // tmp slots per bucket (4081 avg + 16 sigma)
#define GEMMB 782                        // (50000/16+3)/4 blocks of 4 waves
#define CST 136                          // epilogue LDS row stride (ushorts)
#define SMEM_BYTES 18432                 // max(gemm 17408, build 16384+1024+1024)

typedef __bf16 bfx8 __attribute__((ext_vector_type(8)));
typedef float  f32x4 __attribute__((ext_vector_type(4)));

__device__ __forceinline__ ushort f2b(float f) {        // fp32 -> bf16 RNE
    unsigned b = __float_as_uint(f);
    b += 0x7fff + ((b >> 16) & 1);
    return (ushort)(b >> 16);
}
__device__ __forceinline__ float b2f(ushort s) {
    return __uint_as_float((unsigned)s << 16);
}
__device__ __forceinline__ unsigned pk2(float a, float b) {
    return (unsigned)f2b(a) | ((unsigned)f2b(b) << 16);
}

// ---------------- partition edges into dst-buckets (+ fused weight prep) ----
__launch_bounds__(256)
__global__ void k_partwt(const int* __restrict__ ei, int* __restrict__ gcur,
                         unsigned* __restrict__ tmp,
                         const float* __restrict__ W0, const float* __restrict__ Wc,
                         ushort* __restrict__ Wt) {
    int t = threadIdx.x;
    if (blockIdx.x >= NPBLK) {
        int i = (blockIdx.x - NPBLK) * 256 + t;      // 0 .. 65535
        int m = i >> 14;
        int r = i & 16383;
        int k = r >> 7, n = r & 127;
        const float* src = (m == 0) ? W0 : (Wc + (size_t)(m - 1) * DH * DH);
        Wt[(size_t)m * DH * DH + n * DH + k] = f2b(src[r]);
        return;
    }
    __shared__ int cnt[NBK], base[NBK], lcur[NBK];
    for (int i = t; i < NBK; i += 256) cnt[i] = 0;
    __syncthreads();
    int e0 = blockIdx.x * EPB;
    int dreg[16];
    #pragma unroll
    for (int j = 0; j < 16; ++j) {
        int e = e0 + j * 256 + t;
        dreg[j] = (e < NE) ? ei[NE + e] : -1;
        if (e < NE) atomicAdd(&cnt[dreg[j] >> 8], 1);
    }
    __syncthreads();
    for (int i = t; i < NBK; i += 256) {
        base[i] = cnt[i] ? atomicAdd(&gcur[i], cnt[i]) : 0;
        lcur[i] = 0;
    }
    __syncthreads();
    #pragma unroll
    for (int j = 0; j < 16; ++j) {
        int e = e0 + j * 256 + t;
        if (e < NE) {
            int d = dreg[j], s = ei[e];
            int b = d >> 8;
            int r = atomicAdd(&lcur[b], 1);
            tmp[(size_t)b * CAPB + base[b] + r] = ((unsigned)(d & 255) << 16) | (unsigned)s;
        }
    }
}

// ---------------- per-bucket degree count + local padded offsets ----------
__launch_bounds__(256)
__global__ void k_bcount(const unsigned* __restrict__ tmp, const int* __restrict__ gcur,
                         int* __restrict__ deg, int* __restrict__ ploc,
                         int* __restrict__ bsizeP) {
    __shared__ int dcnt[NPB];
    int b = blockIdx.x, t = threadIdx.x;
    dcnt[t] = 0;
    __syncthreads();
    int ne = gcur[b];
    for (int e = t; e < ne; e += 256)
        atomicAdd(&dcnt[tmp[(size_t)b * CAPB + e] >> 16], 1);
    __syncthreads();
    int n = b * NPB + t;
    int d = (n < NN) ? dcnt[t] : 0;
    int p = (n < NN) ? ((d + 4) & ~3) : 0;           // align4(deg+1)
    int inc = p;
    #pragma unroll
    for (int off = 1; off < 64; off <<= 1) {
        int u = __shfl_up(inc, off);
        if ((t & 63) >= off) inc += u;
    }
    __shared__ int wsum[4];
    if ((t & 63) == 63) wsum[t >> 6] = inc;
    __syncthreads();
    int w = t >> 6, woff = 0;
    #pragma unroll
    for (int k = 0; k < 4; ++k) if (k < w) woff += wsum[k];
    int lofs = inc - p + woff;
    if (n < NN) { deg[n] = d; ploc[n] = lofs; }
    if (t == 255) bsizeP[b] = lofs + p;              // bucket padded total
}

// ---------------- MFMA GEMM body (shared by fused kernels) ----------------
// One wave per 16 rows. D: col=lane&15, row=quad*4+reg (verified m89).
// OUTF16: write fp16 (for aggr gather) else bf16 (for next GEMM / pool).
template<bool AF32, bool DOTS, bool OUTF16>
__device__ __forceinline__ void gemm_body(char* smem, int gblk,
        const void* __restrict__ Av, const ushort* __restrict__ Wt,
        const float* __restrict__ bias, ushort* __restrict__ C, int relu,
        const float* __restrict__ avs, const float* __restrict__ avd,
        float* __restrict__ asrc, float* __restrict__ adst) {
    int tid = threadIdx.x;
    int wid = (gblk * 256 + tid) >> 6;
    int lane = tid & 63;
    int row0 = wid * 16;
    if (row0 >= NN) return;
    int mrow = lane & 15;
    int quad = lane >> 4;
    int arow = row0 + mrow;
    ushort* my = (ushort*)smem + (tid >> 6) * 16 * CST;

    f32x4 acc[8];
    #pragma unroll
    for (int t = 0; t < 8; ++t)
        #pragma unroll
        for (int r = 0; r < 4; ++r) acc[t][r] = 0.f;

    #pragma unroll
    for (int ks = 0; ks < 4; ++ks) {
        int k0 = ks * 32 + quad * 8;
        bfx8 a;
        if (AF32) {
            const float* ap = (const float*)Av + (size_t)arow * DH + k0;
            union { ushort s[8]; bfx8 v; } u;
            #pragma unroll
            for (int j = 0; j < 8; ++j) u.s[j] = f2b(ap[j]);
            a = u.v;
        } else {
            a = *(const bfx8*)((const ushort*)Av + (size_t)arow * DH + k0);
        }
        #pragma unroll
        for (int t = 0; t < 8; ++t) {
            bfx8 b = *(const bfx8*)(Wt + (size_t)(t * 16 + mrow) * DH + k0);
            acc[t] = __builtin_amdgcn_mfma_f32_16x16x32_bf16(a, b, acc[t], 0, 0, 0);
        }
    }

    #pragma unroll
    for (int t = 0; t < 8; ++t) {
        int col = t * 16 + mrow;
        float bv = bias ? bias[col] : 0.f;
        #pragma unroll
        for (int r = 0; r < 4; ++r) {
            float v = acc[t][r] + bv;
            if (relu) v = fmaxf(v, 0.f);
            my[(quad * 4 + r) * CST + col] =
                OUTF16 ? __half_as_ushort(__float2half(v)) : f2b(v);
        }
    }
    #pragma unroll
    for (int i = 0; i < 4; ++i) {
        int idx = i * 64 + lane;
        int row = idx >> 4;
        int c16 = idx & 15;
        uint4 u = *(const uint4*)(my + row * CST + c16 * 8);
        *(uint4*)(C + (size_t)(row0 + row) * DH + c16 * 8) = u;
    }

    if (DOTS) {
        float av[8], dv[8];
        #pragma unroll
        for (int t = 0; t < 8; ++t) {
            av[t] = avs[t * 16 + mrow];
            dv[t] = avd[t * 16 + mrow];
        }
        int orow = row0 + quad * 4;
        #pragma unroll
        for (int r = 0; r < 4; ++r) {
            float ps = 0.f, pd = 0.f;
            #pragma unroll
            for (int t = 0; t < 8; ++t) {
                ps += acc[t][r] * av[t];
                pd += acc[t][r] * dv[t];
            }
            #pragma unroll
            for (int off = 1; off < 16; off <<= 1) {
                ps += __shfl_xor(ps, off);
                pd += __shfl_xor(pd, off);
            }
            if (mrow == 0) {
                asrc[orow + r] = ps;
                adst[orow + r] = pd;
            }
        }
    }
}

// ---------------- fused: GEMM-1 (fp32 x -> bf16 hB) + CSR assembly --------
// blocks [0,GEMMB): GEMM.  blocks [GEMMB,GEMMB+NBK): build csr per bucket
// (each build block redundantly scans bsizeP in LDS -> no k_bscan launch).
__launch_bounds__(256)
__global__ void k_buildgemm(const unsigned* __restrict__ tmp, const int* __restrict__ gcur,
                            const int* __restrict__ bsizeP, const int* __restrict__ ploc,
                            int* __restrict__ pstart, ushort* __restrict__ csr,
                            const float* __restrict__ x, const ushort* __restrict__ Wt,
                            const float* __restrict__ b0, ushort* __restrict__ hB) {
    __shared__ char smem[SMEM_BYTES];
    int t = threadIdx.x;
    if (blockIdx.x < GEMMB) {
        gemm_body<true, false, false>(smem, blockIdx.x, x, Wt, b0, hB, 1,
                                      nullptr, nullptr, nullptr, nullptr);
        return;
    }
    int b = blockIdx.x - GEMMB;
    ushort* buf = (ushort*)smem;                      // 8192 ushorts
    int* lcur = (int*)(smem + 16384);                 // NPB ints
    int* sm   = (int*)(smem + 16384 + 1024);          // 256 ints (scan)
    // in-block exclusive scan of bsizeP -> r0 for this bucket
    int v = (t < NBK) ? bsizeP[t] : 0;
    sm[t] = v;
    __syncthreads();
    for (int off = 1; off < 256; off <<= 1) {
        int u = (t >= off) ? sm[t - off] : 0;
        __syncthreads();
        sm[t] += u;
        __syncthreads();
    }
    int r0 = sm[b] - bsizeP[b];
    int S = bsizeP[b];                                // multiple of 4
    int n0 = b * NPB, n1 = min(n0 + NPB, NN), nodes = n1 - n0;
    int ne = gcur[b];

    if (S <= 8192) {
        for (int i = t; i < (S >> 1); i += 256) ((unsigned*)buf)[i] = 0;
        __syncthreads();
        if (t < nodes) {
            int lp = ploc[n0 + t];
            pstart[n0 + t] = r0 + lp;
            lcur[t] = lp + 1;
            buf[lp] = (ushort)(n0 + t);               // self-loop first
        }
        __syncthreads();
        for (int e = t; e < ne; e += 256) {
            unsigned u = tmp[(size_t)b * CAPB + e];
            int slot = atomicAdd(&lcur[u >> 16], 1);
            buf[slot] = (ushort)(u & 0xffffu);
        }
        __syncthreads();
        unsigned* dst = (unsigned*)(csr + r0);
        for (int i = t; i < (S >> 1); i += 256) dst[i] = ((unsigned*)buf)[i];
    } else {
        // fallback (never with this data): direct global writes
        for (int i = t; i < S; i += 256) csr[r0 + i] = 0;
        __syncthreads();
        if (t < nodes) {
            int lp = ploc[n0 + t];
            pstart[n0 + t] = r0 + lp;
            lcur[t] = r0 + lp + 1;
            csr[r0 + lp] = (ushort)(n0 + t);
        }
        __syncthreads();
        for (int e = t; e < ne; e += 256) {
            unsigned u = tmp[(size_t)b * CAPB + e];
            int slot = atomicAdd(&lcur[u >> 16], 1);
            csr[slot] = (ushort)(u & 0xffffu);
        }
    }
}

// ---------------- GEMM + fused attention dots (layers, fp16 out) ----------
__launch_bounds__(256)
__global__ void k_gemmdots(const ushort* __restrict__ hB, const ushort* __restrict__ Wt,
                           ushort* __restrict__ hA,
                           const float* __restrict__ avs, const float* __restrict__ avd,
                           float* __restrict__ asrc, float* __restrict__ adst) {
    __shared__ char smem[SMEM_BYTES];
    gemm_body<false, true, true>(smem, blockIdx.x, hB, Wt, nullptr, hA, 0,
                                 avs, avd, asrc, adst);
}

// ---------------- fused segment softmax + weighted aggregate (fp16 h) -------
// one wave per node; padded segments (x4, zero-pad) -> unguarded 4x-unrolled
// uint4 gathers; packed-fp16 FMA (4 __hfma2 per edge), f32 finalization.
__launch_bounds__(256)
__global__ void k_aggr(const ushort* __restrict__ h, const float* __restrict__ asrc,
                       const float* __restrict__ adst, const int* __restrict__ pstart,
                       const int* __restrict__ deg, const ushort* __restrict__ csr,
                       const float* __restrict__ bias, ushort* __restrict__ hout) {
    int wid = (blockIdx.x * blockDim.x + threadIdx.x) >> 6;
    int lane = threadIdx.x & 63;
    if (wid >= NN) return;
    int start = pstart[wid];
    int cnt = deg[wid] + 1;
    float ad = adst[wid];

    if (cnt <= 64) {
        int s = csr[start + lane];               // pads are 0 (valid index)
        float e = -1e30f;
        if (lane < cnt) {
            float t = asrc[s] + ad;
            e = fmaxf(t, 0.f) + 0.2f * fminf(t, 0.f);
        }
        float m = e;
        #pragma unroll
        for (int off = 32; off; off >>= 1) m = fmaxf(m, __shfl_xor(m, off));
        float w = (lane < cnt) ? __expf(e - m) : 0.f;
        float dsum = w;
        #pragma unroll
        for (int off = 32; off; off >>= 1) dsum += __shfl_xor(dsum, off);

        int g = lane >> 4, fidx = lane & 15;
        __half2 a2[4];
        #pragma unroll
        for (int k = 0; k < 4; ++k) a2[k] = __float2half2_rn(0.f);

        int steps = (cnt + 3) >> 2;
        const uint4* hp = (const uint4*)h;
        int j = 0;
        for (; j + 3 < steps; j += 4) {
            int   e0 = j * 4 + g,      e1 = e0 + 4,  e2 = e0 + 8,  e3 = e0 + 12;
            float w0 = __shfl(w, e0),  w1 = __shfl(w, e1);
            float w2 = __shfl(w, e2),  w3 = __shfl(w, e3);
            int   s0 = __shfl(s, e0),  s1 = __shfl(s, e1);
            int   s2 = __shfl(s, e2),  s3 = __shfl(s, e3);
            uint4 u0 = hp[(size_t)s0 * 16 + fidx];
            uint4 u1 = hp[(size_t)s1 * 16 + fidx];
            uint4 u2 = hp[(size_t)s2 * 16 + fidx];
            uint4 u3 = hp[(size_t)s3 * 16 + fidx];
            __half2 p0 = __float2half2_rn(w0), p1 = __float2half2_rn(w1);
            __half2 p2 = __float2half2_rn(w2), p3 = __float2half2_rn(w3);
            a2[0] = __hfma2(*(__half2*)&u0.x, p0, a2[0]);
            a2[1] = __hfma2(*(__half2*)&u0.y, p0, a2[1]);
            a2[2] = __hfma2(*(__half2*)&u0.z, p0, a2[2]);
            a2[3] = __hfma2(*(__half2*)&u0.w, p0, a2[3]);
            a2[0] = __hfma2(*(__half2*)&u1.x, p1, a2[0]);
            a2[1] = __hfma2(*(__half2*)&u1.y, p1, a2[1]);
            a2[2] = __hfma2(*(__half2*)&u1.z, p1, a2[2]);
            a2[3] = __hfma2(*(__half2*)&u1.w, p1, a2[3]);
            a2[0] = __hfma2(*(__half2*)&u2.x, p2, a2[0]);
            a2[1] = __hfma2(*(__half2*)&u2.y, p2, a2[1]);
            a2[2] = __hfma2(*(__half2*)&u2.z, p2, a2[2]);
            a2[3] = __hfma2(*(__half2*)&u2.w, p2, a2[3]);
            a2[0] = __hfma2(*(__half2*)&u3.x, p3, a2[0]);
            a2[1] = __hfma2(*(__half2*)&u3.y, p3, a2[1]);
            a2[2] = __hfma2(*(__half2*)&u3.z, p3, a2[2]);
            a2[3] = __hfma2(*(__half2*)&u3.w, p3, a2[3]);
        }
        for (; j < steps; ++j) {
            int e0 = j * 4 + g;
            float w0 = __shfl(w, e0);
            int   s0 = __shfl(s, e0);
            uint4 u0 = hp[(size_t)s0 * 16 + fidx];
            __half2 p0 = __float2half2_rn(w0);
            a2[0] = __hfma2(*(__half2*)&u0.x, p0, a2[0]);
            a2[1] = __hfma2(*(__half2*)&u0.y, p0, a2[1]);
            a2[2] = __hfma2(*(__half2*)&u0.z, p0, a2[2]);
            a2[3] = __hfma2(*(__half2*)&u0.w, p0, a2[3]);
        }
        float acc[8];
        #pragma unroll
        for (int k = 0; k < 4; ++k) {
            acc[2 * k]     = __low2float(a2[k]);
            acc[2 * k + 1] = __high2float(a2[k]);
        }
        #pragma unroll
        for (int k = 0; k < 8; ++k) {
            acc[k] += __shfl_xor(acc[k], 16);
            acc[k] += __shfl_xor(acc[k], 32);
        }
        if (g == 0) {
            float inv = 1.f / (dsum + 1e-16f);
            const float4* bp = (const float4*)bias;
            float4 b0 = bp[fidx * 2], b1 = bp[fidx * 2 + 1];
            uint4 o;
            o.x = pk2(fmaxf(acc[0] * inv + b0.x, 0.f), fmaxf(acc[1] * inv + b0.y, 0.f));
            o.y = pk2(fmaxf(acc[2] * inv + b0.z, 0.f), fmaxf(acc[3] * inv + b0.w, 0.f));
            o.z = pk2(fmaxf(acc[4] * inv + b1.x, 0.f), fmaxf(acc[5] * inv + b1.y, 0.f));
            o.w = pk2(fmaxf(acc[6] * inv + b1.z, 0.f), fmaxf(acc[7] * inv + b1.w, 0.f));
            ((uint4*)hout)[(size_t)wid * 16 + fidx] = o;
        }
        return;
    }

    // generic fallback (deg > 64) — never with this data
    float m = -1e30f;
    for (int i0 = start; i0 < start + cnt; i0 += 64) {
        int i = i0 + lane;
        float e = -1e30f;
        if (i < start + cnt) {
            int s = csr[i];
            float t = asrc[s] + ad;
            e = fmaxf(t, 0.f) + 0.2f * fminf(t, 0.f);
        }
        m = fmaxf(m, e);
    }
    #pragma unroll
    for (int off = 32; off; off >>= 1) m = fmaxf(m, __shfl_xor(m, off));

    float accx = 0.f, accy = 0.f, dsum = 0.f;
    for (int i0 = start; i0 < start + cnt; i0 += 64) {
        int i = i0 + lane;
        int s = 0; float w = 0.f;
        if (i < start + cnt) {
            s = csr[i];
            float t = asrc[s] + ad;
            float e = fmaxf(t, 0.f) + 0.2f * fminf(t, 0.f);
            w = __expf(e - m);
        }
        dsum += w;
        int cl = min(64, start + cnt - i0);
        for (int j = 0; j < cl; ++j) {
            int   sj = __shfl(s, j);
            float wj = __shfl(w, j);
            unsigned u = *(const unsigned*)(h + (size_t)sj * DH + lane * 2);
            __half2 hh = *(__half2*)&u;
            accx += wj * __low2float(hh);
            accy += wj * __high2float(hh);
        }
    }
    #pragma unroll
    for (int off = 32; off; off >>= 1) dsum += __shfl_xor(dsum, off);

    float inv = 1.f / (dsum + 1e-16f);
    float ox = fmaxf(accx * inv + bias[lane * 2], 0.f);
    float oy = fmaxf(accy * inv + bias[lane * 2 + 1], 0.f);
    *(unsigned*)(hout + (size_t)wid * DH + lane * 2) = pk2(ox, oy);
}

// ---------------- mean pool (batch sorted, bf16 h, 2 rows in flight) -------
__launch_bounds__(256)
__global__ void k_pool(const ushort* __restrict__ h, const int* __restrict__ batch,
                       float* __restrict__ gsum, int* __restrict__ gcnt) {
    int slot = threadIdx.x >> 7;          // 0 or 1
    int f = threadIdx.x & 127;
    int n0 = blockIdx.x * 64;
    int n1 = min(n0 + 64, NN);
    int first = n0 + slot;
    if (first >= n1) return;
    float acc = 0.f; int run = 0;
    int gcur = batch[first];
    for (int nd = first; nd < n1; nd += 2) {
        int g = batch[nd];
        if (g != gcur) {
            atomicAdd(&gsum[gcur * DH + f], acc);
            if (f == 0) atomicAdd(&gcnt[gcur], run);
            acc = 0.f; run = 0; gcur = g;
        }
        acc += b2f(h[(size_t)nd * DH + f]);
        run += 1;
    }
    atomicAdd(&gsum[gcur * DH + f], acc);
    if (f == 0) atomicAdd(&gcnt[gcur], run);
}

// ---------------- final linear [64,128]@[128,10] -> fp32 out ----------------
__global__ void k_final(const float* __restrict__ gsum, const int* __restrict__ gcnt,
                        const float* __restrict__ W1, const float* __restrict__ b1,
                        float* __restrict__ out) {
    int t = threadIdx.x;
    if (t >= NG * 10) return;
    int g = t / 10, o = t % 10;
    float inv = 1.f / fmaxf((float)gcnt[g], 1.f);
    float acc = 0.f;
    for (int f = 0; f < DH; ++f) acc += gsum[g * DH + f] * W1[f * 10 + o];
    out[t] = acc * inv + b1[o];
}

extern "C" void kernel_launch(void* const* d_in, const int* in_sizes, int n_in,
                              void* d_out, int out_size, void* d_ws, size_t ws_size,
                              hipStream_t stream) {
    const float* x       = (const float*)d_in[0];
    const int*   ei      = (const int*)d_in[1];
    const int*   batch   = (const int*)d_in[3];
    const float* W0      = (const float*)d_in[4];
    const float* b0      = (const float*)d_in[5];
    const float* Wc      = (const float*)d_in[6];
    const float* att_src = (const float*)d_in[7];
    const float* att_dst = (const float*)d_in[8];
    const float* bc      = (const float*)d_in[9];
    const float* W1      = (const float*)d_in[10];
    const float* b1      = (const float*)d_in[11];
    float* out = (float*)d_out;

    char* ws = (char*)d_ws;
    size_t off = 0;
    auto alloc = [&](size_t bytes) {
        void* p = ws + off;
        off += (bytes + 255) & ~(size_t)255;
        return p;
    };
    ushort*   hA     = (ushort*)alloc((size_t)NN * DH * 2);   // fp16
    ushort*   hB     = (ushort*)alloc((size_t)NN * DH * 2);   // bf16
    ushort*   Wt     = (ushort*)alloc((size_t)4 * DH * DH * 2);
    int*      pstart = (int*)alloc((size_t)NN * 4);
    ushort*   csr    = (ushort*)alloc((size_t)(NE + 4 * NN + 64) * 2);
    unsigned* tmp    = (unsigned*)alloc((size_t)NBK * CAPB * 4);
    float*    asrc   = (float*)alloc(NN * 4);
    float*    adst   = (float*)alloc(NN * 4);
    int*      deg    = (int*)alloc(NN * 4);
    int*      ploc   = (int*)alloc(NN * 4);
    int*      gcur   = (int*)alloc((NBK + 1) * 4);
    int*      bsizeP = (int*)alloc((NBK + 1) * 4);
    float*    gsum   = (float*)alloc(NG * DH * 4);   // gsum+gcnt adjacent
    int*      gcnt   = (int*)alloc(NG * 4);

    hipMemsetAsync(gcur, 0, (NBK + 1) * 4, stream);
    hipMemsetAsync(gsum, 0, NG * DH * 4 + 256, stream);  // covers gcnt too

    k_partwt<<<NPBLK + 256, 256, 0, stream>>>(ei, gcur, tmp, W0, Wc, Wt);
    k_bcount<<<NBK, 256, 0, stream>>>(tmp, gcur, deg, ploc, bsizeP);
    k_buildgemm<<<GEMMB + NBK, 256, 0, stream>>>(tmp, gcur, bsizeP, ploc, pstart, csr,
                                                 x, Wt, b0, hB);

    for (int l = 0; l < 3; ++l) {
        k_gemmdots<<<GEMMB, 256, 0, stream>>>(hB, Wt + (size_t)(l + 1) * DH * DH, hA,
                                              att_src + l * DH, att_dst + l * DH,
                                              asrc, adst);
        k_aggr<<<(NN + 3) / 4, 256, 0, stream>>>(hA, asrc, adst, pstart, deg, csr,
                                                 bc + l * DH, hB);
    }

    k_pool<<<(NN + 63) / 64, 256, 0, stream>>>(hB, batch, gsum, gcnt);
    k_final<<<1, NG * 10, 0, stream>>>(gsum, gcnt, W1, b1, out);
}

// Round 11
// 325.674 us; speedup vs baseline: 2.2756x; 1.0690x over previous
//
#include <hip/hip_runtime.h>
#include <hip/hip_bf16.h>
#include <hip/hip_fp16.h>
#include <hip/hip_fp8.h>

#define NN 50000
#define NE 800000
#define NG 64
#define DH 128

#define NPB 256                          // nodes per bucket
#define NBK ((NN + NPB - 1) / NPB)       // 196 buckets
#define EPB 4096                         // edges per partition block
#define NPBLK ((NE + EPB - 1) / EPB)     // 196
#define CAPB 5120                        // tmp slots per bucket (4081 avg + 16 sigma)
#define GEMMB 782                        // (50000/16+3)/4 blocks of 4 waves
#define CST 136                          // bf16 epilogue LDS row stride (ushorts)
#define CSTB 136                         // fp8 epilogue LDS row stride (bytes)
#define SMEM_BYTES 18432                 // max(gemm-bf16 17408, build 16384+1024+1024)

#if defined(__has_builtin)
# if __has_builtin(__builtin_amdgcn_cvt_pk_f32_fp8) && __has_builtin(__builtin_amdgcn_cvt_pk_fp8_f32)
#  define HW_FP8 1
# endif
#endif

typedef __bf16 bfx8 __attribute__((ext_vector_type(8)));
typedef float  f32x4 __attribute__((ext_vector_type(4)));

__device__ __forceinline__ ushort f2b(float f) {        // fp32 -> bf16 RNE
    unsigned b = __float_as_uint(f);
    b += 0x7fff + ((b >> 16) & 1);
    return (ushort)(b >> 16);
}
__device__ __forceinline__ float b2f(ushort s) {
    return __uint_as_float((unsigned)s << 16);
}
__device__ __forceinline__ unsigned pk2(float a, float b) {
    return (unsigned)f2b(a) | ((unsigned)f2b(b) << 16);
}

__device__ __forceinline__ unsigned f2fp8(float v) {    // fp32 -> e4m3 (clamped)
    v = fminf(fmaxf(v, -448.f), 448.f);
#ifdef HW_FP8
    return (unsigned)__builtin_amdgcn_cvt_pk_fp8_f32(v, v, 0, false) & 0xFFu;
#else
    __hip_fp8_e4m3 t(v);
    return (unsigned)*(const unsigned char*)&t;
#endif
}
// unpack 4 e4m3 (in a dword) -> 4 floats
__device__ __forceinline__ void fp8x4_up(unsigned u, float* o) {
#ifdef HW_FP8
    auto lo = __builtin_amdgcn_cvt_pk_f32_fp8((int)u, false);
    auto hi = __builtin_amdgcn_cvt_pk_f32_fp8((int)u, true);
    o[0] = lo[0]; o[1] = lo[1]; o[2] = hi[0]; o[3] = hi[1];
#else
    #pragma unroll
    for (int k = 0; k < 4; ++k) {
        unsigned char c = (u >> (8 * k)) & 0xFF;
        o[k] = float(*(const __hip_fp8_e4m3*)&c);
    }
#endif
}

// ---------------- partition edges into dst-buckets (+ fused weight prep) ----
__launch_bounds__(256)
__global__ void k_partwt(const int* __restrict__ ei, int* __restrict__ gcur,
                         unsigned* __restrict__ tmp,
                         const float* __restrict__ W0, const float* __restrict__ Wc,
                         ushort* __restrict__ Wt) {
    int t = threadIdx.x;
    if (blockIdx.x >= NPBLK) {
        int i = (blockIdx.x - NPBLK) * 256 + t;      // 0 .. 65535
        int m = i >> 14;
        int r = i & 16383;
        int k = r >> 7, n = r & 127;
        const float* src = (m == 0) ? W0 : (Wc + (size_t)(m - 1) * DH * DH);
        Wt[(size_t)m * DH * DH + n * DH + k] = f2b(src[r]);
        return;
    }
    __shared__ int cnt[NBK], base[NBK], lcur[NBK];
    for (int i = t; i < NBK; i += 256) cnt[i] = 0;
    __syncthreads();
    int e0 = blockIdx.x * EPB;
    int dreg[16];
    #pragma unroll
    for (int j = 0; j < 16; ++j) {
        int e = e0 + j * 256 + t;
        dreg[j] = (e < NE) ? ei[NE + e] : -1;
        if (e < NE) atomicAdd(&cnt[dreg[j] >> 8], 1);
    }
    __syncthreads();
    for (int i = t; i < NBK; i += 256) {
        base[i] = cnt[i] ? atomicAdd(&gcur[i], cnt[i]) : 0;
        lcur[i] = 0;
    }
    __syncthreads();
    #pragma unroll
    for (int j = 0; j < 16; ++j) {
        int e = e0 + j * 256 + t;
        if (e < NE) {
            int d = dreg[j], s = ei[e];
            int b = d >> 8;
            int r = atomicAdd(&lcur[b], 1);
            tmp[(size_t)b * CAPB + base[b] + r] = ((unsigned)(d & 255) << 16) | (unsigned)s;
        }
    }
}

// ---------------- per-bucket degree count + local padded offsets ----------
__launch_bounds__(256)
__global__ void k_bcount(const unsigned* __restrict__ tmp, const int* __restrict__ gcur,
                         int* __restrict__ deg, int* __restrict__ ploc,
                         int* __restrict__ bsizeP) {
    __shared__ int dcnt[NPB];
    int b = blockIdx.x, t = threadIdx.x;
    dcnt[t] = 0;
    __syncthreads();
    int ne = gcur[b];
    for (int e = t; e < ne; e += 256)
        atomicAdd(&dcnt[tmp[(size_t)b * CAPB + e] >> 16], 1);
    __syncthreads();
    int n = b * NPB + t;
    int d = (n < NN) ? dcnt[t] : 0;
    int p = (n < NN) ? ((d + 4) & ~3) : 0;           // align4(deg+1)
    int inc = p;
    #pragma unroll
    for (int off = 1; off < 64; off <<= 1) {
        int u = __shfl_up(inc, off);
        if ((t & 63) >= off) inc += u;
    }
    __shared__ int wsum[4];
    if ((t & 63) == 63) wsum[t >> 6] = inc;
    __syncthreads();
    int w = t >> 6, woff = 0;
    #pragma unroll
    for (int k = 0; k < 4; ++k) if (k < w) woff += wsum[k];
    int lofs = inc - p + woff;
    if (n < NN) { deg[n] = d; ploc[n] = lofs; }
    if (t == 255) bsizeP[b] = lofs + p;              // bucket padded total
}

// ---------------- MFMA GEMM body (shared by fused kernels) ----------------
// One wave per 16 rows. D: col=lane&15, row=quad*4+reg (verified m89).
// OUTFP8: write e4m3 bytes (aggr gather input) else bf16 (next GEMM / pool).
template<bool AF32, bool DOTS, bool OUTFP8>
__device__ __forceinline__ void gemm_body(char* smem, int gblk,
        const void* __restrict__ Av, const ushort* __restrict__ Wt,
        const float* __restrict__ bias, void* __restrict__ C, int relu,
        const float* __restrict__ avs, const float* __restrict__ avd,
        float* __restrict__ asrc, float* __restrict__ adst) {
    int tid = threadIdx.x;
    int wid = (gblk * 256 + tid) >> 6;
    int lane = tid & 63;
    int row0 = wid * 16;
    if (row0 >= NN) return;
    int mrow = lane & 15;
    int quad = lane >> 4;
    int arow = row0 + mrow;

    f32x4 acc[8];
    #pragma unroll
    for (int t = 0; t < 8; ++t)
        #pragma unroll
        for (int r = 0; r < 4; ++r) acc[t][r] = 0.f;

    #pragma unroll
    for (int ks = 0; ks < 4; ++ks) {
        int k0 = ks * 32 + quad * 8;
        bfx8 a;
        if (AF32) {
            const float* ap = (const float*)Av + (size_t)arow * DH + k0;
            union { ushort s[8]; bfx8 v; } u;
            #pragma unroll
            for (int j = 0; j < 8; ++j) u.s[j] = f2b(ap[j]);
            a = u.v;
        } else {
            a = *(const bfx8*)((const ushort*)Av + (size_t)arow * DH + k0);
        }
        #pragma unroll
        for (int t = 0; t < 8; ++t) {
            bfx8 b = *(const bfx8*)(Wt + (size_t)(t * 16 + mrow) * DH + k0);
            acc[t] = __builtin_amdgcn_mfma_f32_16x16x32_bf16(a, b, acc[t], 0, 0, 0);
        }
    }

    if (OUTFP8) {
        uchar* my = (uchar*)smem + (tid >> 6) * 16 * CSTB;
        #pragma unroll
        for (int t = 0; t < 8; ++t) {
            int col = t * 16 + mrow;
            float bv = bias ? bias[col] : 0.f;
            #pragma unroll
            for (int r = 0; r < 4; ++r) {
                float v = acc[t][r] + bv;
                if (relu) v = fmaxf(v, 0.f);
                my[(quad * 4 + r) * CSTB + col] = (uchar)f2fp8(v);
            }
        }
        #pragma unroll
        for (int i = 0; i < 4; ++i) {
            int idx = i * 64 + lane;          // 16 rows x 16 uint2
            int row = idx >> 4;
            int c8 = idx & 15;
            uint2 u = *(const uint2*)(my + row * CSTB + c8 * 8);
            *(uint2*)((uchar*)C + (size_t)(row0 + row) * DH + c8 * 8) = u;
        }
    } else {
        ushort* my = (ushort*)smem + (tid >> 6) * 16 * CST;
        #pragma unroll
        for (int t = 0; t < 8; ++t) {
            int col = t * 16 + mrow;
            float bv = bias ? bias[col] : 0.f;
            #pragma unroll
            for (int r = 0; r < 4; ++r) {
                float v = acc[t][r] + bv;
                if (relu) v = fmaxf(v, 0.f);
                my[(quad * 4 + r) * CST + col] = f2b(v);
            }
        }
        #pragma unroll
        for (int i = 0; i < 4; ++i) {
            int idx = i * 64 + lane;
            int row = idx >> 4;
            int c16 = idx & 15;
            uint4 u = *(const uint4*)(my + row * CST + c16 * 8);
            *(uint4*)((ushort*)C + (size_t)(row0 + row) * DH + c16 * 8) = u;
        }
    }

    if (DOTS) {
        float av[8], dv[8];
        #pragma unroll
        for (int t = 0; t < 8; ++t) {
            av[t] = avs[t * 16 + mrow];
            dv[t] = avd[t * 16 + mrow];
        }
        int orow = row0 + quad * 4;
        #pragma unroll
        for (int r = 0; r < 4; ++r) {
            float ps = 0.f, pd = 0.f;
            #pragma unroll
            for (int t = 0; t < 8; ++t) {
                ps += acc[t][r] * av[t];
                pd += acc[t][r] * dv[t];
            }
            #pragma unroll
            for (int off = 1; off < 16; off <<= 1) {
                ps += __shfl_xor(ps, off);
                pd += __shfl_xor(pd, off);
            }
            if (mrow == 0) {
                asrc[orow + r] = ps;
                adst[orow + r] = pd;
            }
        }
    }
}

// ---------------- fused: GEMM-1 (fp32 x -> bf16 hB) + CSR assembly --------
__launch_bounds__(256)
__global__ void k_buildgemm(const unsigned* __restrict__ tmp, const int* __restrict__ gcur,
                            const int* __restrict__ bsizeP, const int* __restrict__ ploc,
                            int* __restrict__ pstart, ushort* __restrict__ csr,
                            const float* __restrict__ x, const ushort* __restrict__ Wt,
                            const float* __restrict__ b0, ushort* __restrict__ hB) {
    __shared__ char smem[SMEM_BYTES];
    int t = threadIdx.x;
    if (blockIdx.x < GEMMB) {
        gemm_body<true, false, false>(smem, blockIdx.x, x, Wt, b0, hB, 1,
                                      nullptr, nullptr, nullptr, nullptr);
        return;
    }
    int b = blockIdx.x - GEMMB;
    ushort* buf = (ushort*)smem;                      // 8192 ushorts
    int* lcur = (int*)(smem + 16384);                 // NPB ints
    int* sm   = (int*)(smem + 16384 + 1024);          // 256 ints (scan)
    int v = (t < NBK) ? bsizeP[t] : 0;
    sm[t] = v;
    __syncthreads();
    for (int off = 1; off < 256; off <<= 1) {
        int u = (t >= off) ? sm[t - off] : 0;
        __syncthreads();
        sm[t] += u;
        __syncthreads();
    }
    int r0 = sm[b] - bsizeP[b];
    int S = bsizeP[b];                                // multiple of 4
    int n0 = b * NPB, n1 = min(n0 + NPB, NN), nodes = n1 - n0;
    int ne = gcur[b];

    if (S <= 8192) {
        for (int i = t; i < (S >> 1); i += 256) ((unsigned*)buf)[i] = 0;
        __syncthreads();
        if (t < nodes) {
            int lp = ploc[n0 + t];
            pstart[n0 + t] = r0 + lp;
            lcur[t] = lp + 1;
            buf[lp] = (ushort)(n0 + t);               // self-loop first
        }
        __syncthreads();
        for (int e = t; e < ne; e += 256) {
            unsigned u = tmp[(size_t)b * CAPB + e];
            int slot = atomicAdd(&lcur[u >> 16], 1);
            buf[slot] = (ushort)(u & 0xffffu);
        }
        __syncthreads();
        unsigned* dst = (unsigned*)(csr + r0);
        for (int i = t; i < (S >> 1); i += 256) dst[i] = ((unsigned*)buf)[i];
    } else {
        for (int i = t; i < S; i += 256) csr[r0 + i] = 0;
        __syncthreads();
        if (t < nodes) {
            int lp = ploc[n0 + t];
            pstart[n0 + t] = r0 + lp;
            lcur[t] = r0 + lp + 1;
            csr[r0 + lp] = (ushort)(n0 + t);
        }
        __syncthreads();
        for (int e = t; e < ne; e += 256) {
            unsigned u = tmp[(size_t)b * CAPB + e];
            int slot = atomicAdd(&lcur[u >> 16], 1);
            csr[slot] = (ushort)(u & 0xffffu);
        }
    }
}

// ---------------- GEMM + fused attention dots (layers, fp8 out) ----------
__launch_bounds__(256)
__global__ void k_gemmdots(const ushort* __restrict__ hB, const ushort* __restrict__ Wt,
                           uchar* __restrict__ hA,
                           const float* __restrict__ avs, const float* __restrict__ avd,
                           float* __restrict__ asrc, float* __restrict__ adst) {
    __shared__ char smem[SMEM_BYTES];
    gemm_body<false, true, true>(smem, blockIdx.x, hB, Wt, nullptr, hA, 0,
                                 avs, avd, asrc, adst);
}

// ---------------- fused segment softmax + weighted aggregate (fp8 h) -------
// one wave per node; padded segments (x4, zero-pad). Row = 128 B fp8 = 1 line;
// per edge: 1 uint2 gather + 4 cvt_pk + 8 FMA; 4 edges/step, 4x unroll.
__launch_bounds__(256)
__global__ void k_aggr(const uchar* __restrict__ h8, const float* __restrict__ asrc,
                       const float* __restrict__ adst, const int* __restrict__ pstart,
                       const int* __restrict__ deg, const ushort* __restrict__ csr,
                       const float* __restrict__ bias, ushort* __restrict__ hout) {
    int wid = (blockIdx.x * blockDim.x + threadIdx.x) >> 6;
    int lane = threadIdx.x & 63;
    if (wid >= NN) return;
    int start = pstart[wid];
    int cnt = deg[wid] + 1;
    float ad = adst[wid];

    if (cnt <= 64) {
        int s = csr[start + lane];               // pads are 0 (valid index)
        float e = -1e30f;
        if (lane < cnt) {
            float t = asrc[s] + ad;
            e = fmaxf(t, 0.f) + 0.2f * fminf(t, 0.f);
        }
        float m = e;
        #pragma unroll
        for (int off = 32; off; off >>= 1) m = fmaxf(m, __shfl_xor(m, off));
        float w = (lane < cnt) ? __expf(e - m) : 0.f;
        float dsum = w;
        #pragma unroll
        for (int off = 32; off; off >>= 1) dsum += __shfl_xor(dsum, off);

        int g = lane >> 4, fidx = lane & 15;
        float acc[8];
        #pragma unroll
        for (int k = 0; k < 8; ++k) acc[k] = 0.f;

        int steps = (cnt + 3) >> 2;
        const uint2* hp = (const uint2*)h8;      // 16 uint2 per 128B row
        int j = 0;
        for (; j + 3 < steps; j += 4) {
            int   e0 = j * 4 + g,      e1 = e0 + 4,  e2 = e0 + 8,  e3 = e0 + 12;
            float w0 = __shfl(w, e0),  w1 = __shfl(w, e1);
            float w2 = __shfl(w, e2),  w3 = __shfl(w, e3);
            int   s0 = __shfl(s, e0),  s1 = __shfl(s, e1);
            int   s2 = __shfl(s, e2),  s3 = __shfl(s, e3);
            uint2 u0 = hp[(size_t)s0 * 16 + fidx];
            uint2 u1 = hp[(size_t)s1 * 16 + fidx];
            uint2 u2 = hp[(size_t)s2 * 16 + fidx];
            uint2 u3 = hp[(size_t)s3 * 16 + fidx];
            float v[8];
            fp8x4_up(u0.x, v); fp8x4_up(u0.y, v + 4);
            #pragma unroll
            for (int k = 0; k < 8; ++k) acc[k] += w0 * v[k];
            fp8x4_up(u1.x, v); fp8x4_up(u1.y, v + 4);
            #pragma unroll
            for (int k = 0; k < 8; ++k) acc[k] += w1 * v[k];
            fp8x4_up(u2.x, v); fp8x4_up(u2.y, v + 4);
            #pragma unroll
            for (int k = 0; k < 8; ++k) acc[k] += w2 * v[k];
            fp8x4_up(u3.x, v); fp8x4_up(u3.y, v + 4);
            #pragma unroll
            for (int k = 0; k < 8; ++k) acc[k] += w3 * v[k];
        }
        for (; j < steps; ++j) {
            int e0 = j * 4 + g;
            float w0 = __shfl(w, e0);
            int   s0 = __shfl(s, e0);
            uint2 u0 = hp[(size_t)s0 * 16 + fidx];
            float v[8];
            fp8x4_up(u0.x, v); fp8x4_up(u0.y, v + 4);
            #pragma unroll
            for (int k = 0; k < 8; ++k) acc[k] += w0 * v[k];
        }
        #pragma unroll
        for (int k = 0; k < 8; ++k) {
            acc[k] += __shfl_xor(acc[k], 16);
            acc[k] += __shfl_xor(acc[k], 32);
        }
        if (g == 0) {
            float inv = 1.f / (dsum + 1e-16f);
            const float4* bp = (const float4*)bias;
            float4 b0 = bp[fidx * 2], b1 = bp[fidx * 2 + 1];
            uint4 o;
            o.x = pk2(fmaxf(acc[0] * inv + b0.x, 0.f), fmaxf(acc[1] * inv + b0.y, 0.f));
            o.y = pk2(fmaxf(acc[2] * inv + b0.z, 0.f), fmaxf(acc[3] * inv + b0.w, 0.f));
            o.z = pk2(fmaxf(acc[4] * inv + b1.x, 0.f), fmaxf(acc[5] * inv + b1.y, 0.f));
            o.w = pk2(fmaxf(acc[6] * inv + b1.z, 0.f), fmaxf(acc[7] * inv + b1.w, 0.f));
            ((uint4*)hout)[(size_t)wid * 16 + fidx] = o;
        }
        return;
    }

    // generic fallback (deg > 64) — never with this data
    float m = -1e30f;
    for (int i0 = start; i0 < start + cnt; i0 += 64) {
        int i = i0 + lane;
        float e = -1e30f;
        if (i < start + cnt) {
            int s = csr[i];
            float t = asrc[s] + ad;
            e = fmaxf(t, 0.f) + 0.2f * fminf(t, 0.f);
        }
        m = fmaxf(m, e);
    }
    #pragma unroll
    for (int off = 32; off; off >>= 1) m = fmaxf(m, __shfl_xor(m, off));

    float accx = 0.f, accy = 0.f, dsum = 0.f;
    for (int i0 = start; i0 < start + cnt; i0 += 64) {
        int i = i0 + lane;
        int s = 0; float w = 0.f;
        if (i < start + cnt) {
            s = csr[i];
            float t = asrc[s] + ad;
            float e = fmaxf(t, 0.f) + 0.2f * fminf(t, 0.f);
            w = __expf(e - m);
        }
        dsum += w;
        int cl = min(64, start + cnt - i0);
        for (int j = 0; j < cl; ++j) {
            int   sj = __shfl(s, j);
            float wj = __shfl(w, j);
            unsigned us = *(const ushort*)(h8 + (size_t)sj * DH + lane * 2);
            float v[4];
            fp8x4_up(us, v);                      // v[0],v[1] valid
            accx += wj * v[0];
            accy += wj * v[1];
        }
    }
    #pragma unroll
    for (int off = 32; off; off >>= 1) dsum += __shfl_xor(dsum, off);

    float inv = 1.f / (dsum + 1e-16f);
    float ox = fmaxf(accx * inv + bias[lane * 2], 0.f);
    float oy = fmaxf(accy * inv + bias[lane * 2 + 1], 0.f);
    *(unsigned*)(hout + (size_t)wid * DH + lane * 2) = pk2(ox, oy);
}

// ---------------- mean pool (batch sorted, bf16 h, 2 rows in flight) -------
__launch_bounds__(256)
__global__ void k_pool(const ushort* __restrict__ h, const int* __restrict__ batch,
                       float* __restrict__ gsum, int* __restrict__ gcnt) {
    int slot = threadIdx.x >> 7;          // 0 or 1
    int f = threadIdx.x & 127;
    int n0 = blockIdx.x * 64;
    int n1 = min(n0 + 64, NN);
    int first = n0 + slot;
    if (first >= n1) return;
    int g0 = batch[n0], g1 = batch[n1 - 1];
    if (g0 == g1) {                       // fast path: uniform tile (92%)
        float acc = 0.f;
        for (int nd = first; nd < n1; nd += 2)
            acc += b2f(h[(size_t)nd * DH + f]);
        atomicAdd(&gsum[g0 * DH + f], acc);
        if (f == 0 && slot == 0) atomicAdd(&gcnt[g0], n1 - n0);
        return;
    }
    float acc = 0.f; int run = 0;
    int gcur = batch[first];
    for (int nd = first; nd < n1; nd += 2) {
        int g = batch[nd];
        if (g != gcur) {
            atomicAdd(&gsum[gcur * DH + f], acc);
            if (f == 0) atomicAdd(&gcnt[gcur], run);
            acc = 0.f; run = 0; gcur = g;
        }
        acc += b2f(h[(size_t)nd * DH + f]);
        run += 1;
    }
    atomicAdd(&gsum[gcur * DH + f], acc);
    if (f == 0) atomicAdd(&gcnt[gcur], run);
}

// ---------------- final linear [64,128]@[128,10] -> fp32 out ----------------
__global__ void k_final(const float* __restrict__ gsum, const int* __restrict__ gcnt,
                        const float* __restrict__ W1, const float* __restrict__ b1,
                        float* __restrict__ out) {
    int t = threadIdx.x;
    if (t >= NG * 10) return;
    int g = t / 10, o = t % 10;
    float inv = 1.f / fmaxf((float)gcnt[g], 1.f);
    float acc = 0.f;
    for (int f = 0; f < DH; ++f) acc += gsum[g * DH + f] * W1[f * 10 + o];
    out[t] = acc * inv + b1[o];
}

extern "C" void kernel_launch(void* const* d_in, const int* in_sizes, int n_in,
                              void* d_out, int out_size, void* d_ws, size_t ws_size,
                              hipStream_t stream) {
    const float* x       = (const float*)d_in[0];
    const int*   ei      = (const int*)d_in[1];
    const int*   batch   = (const int*)d_in[3];
    const float* W0      = (const float*)d_in[4];
    const float* b0      = (const float*)d_in[5];
    const float* Wc      = (const float*)d_in[6];
    const float* att_src = (const float*)d_in[7];
    const float* att_dst = (const float*)d_in[8];
    const float* bc      = (const float*)d_in[9];
    const float* W1      = (const float*)d_in[10];
    const float* b1      = (const float*)d_in[11];
    float* out = (float*)d_out;

    char* ws = (char*)d_ws;
    size_t off = 0;
    auto alloc = [&](size_t bytes) {
        void* p = ws + off;
        off += (bytes + 255) & ~(size_t)255;
        return p;
    };
    uchar*    hA     = (uchar*)alloc((size_t)NN * DH);        // fp8 e4m3
    ushort*   hB     = (ushort*)alloc((size_t)NN * DH * 2);   // bf16
    ushort*   Wt     = (ushort*)alloc((size_t)4 * DH * DH * 2);
    int*      pstart = (int*)alloc((size_t)NN * 4);
    ushort*   csr    = (ushort*)alloc((size_t)(NE + 4 * NN + 64) * 2);
    unsigned* tmp    = (unsigned*)alloc((size_t)NBK * CAPB * 4);
    float*    asrc   = (float*)alloc(NN * 4);
    float*    adst   = (float*)alloc(NN * 4);
    int*      deg    = (int*)alloc(NN * 4);
    int*      ploc   = (int*)alloc(NN * 4);
    int*      gcur   = (int*)alloc((NBK + 1) * 4);
    int*      bsizeP = (int*)alloc((NBK + 1) * 4);
    float*    gsum   = (float*)alloc(NG * DH * 4);   // gsum+gcnt adjacent
    int*      gcnt   = (int*)alloc(NG * 4);

    hipMemsetAsync(gcur, 0, (NBK + 1) * 4, stream);
    hipMemsetAsync(gsum, 0, NG * DH * 4 + 256, stream);  // covers gcnt too

    k_partwt<<<NPBLK + 256, 256, 0, stream>>>(ei, gcur, tmp, W0, Wc, Wt);
    k_bcount<<<NBK, 256, 0, stream>>>(tmp, gcur, deg, ploc, bsizeP);
    k_buildgemm<<<GEMMB + NBK, 256, 0, stream>>>(tmp, gcur, bsizeP, ploc, pstart, csr,
                                                 x, Wt, b0, hB);

    for (int l = 0; l < 3; ++l) {
        k_gemmdots<<<GEMMB, 256, 0, stream>>>(hB, Wt + (size_t)(l + 1) * DH * DH, hA,
                                              att_src + l * DH, att_dst + l * DH,
                                              asrc, adst);
        k_aggr<<<(NN + 3) / 4, 256, 0, stream>>>(hA, asrc, adst, pstart, deg, csr,
                                                 bc + l * DH, hB);
    }

    k_pool<<<(NN + 63) / 64, 256, 0, stream>>>(hB, batch, gsum, gcnt);
    k_final<<<1, NG * 10, 0, stream>>>(gsum, gcnt, W1, b1, out);
}